// Round 8
// baseline (652.334 us; speedup 1.0000x reference)
//
#include <hip/hip_runtime.h>
#include <math.h>

#define HW 65536

typedef __attribute__((ext_vector_type(8))) short short8;
typedef __attribute__((ext_vector_type(4))) float f32x4;

__device__ __forceinline__ unsigned bf16rne(float f) {
  union { float f; unsigned u; } a; a.f = f;
  return (a.u + 0x7fffu + ((a.u >> 16) & 1u)) >> 16;
}
__device__ __forceinline__ float bf16tof(unsigned h) {
  union { unsigned u; float f; } a; a.u = h << 16;
  return a.f;
}
// exact gelu (reference-matching path, used only where cheapness doesn't matter)
__device__ __forceinline__ float gelu_exact(float v) {
  return 0.5f * v * (1.0f + erff(v * 0.70710678118654752f));
}
// fast gelu: Abramowitz-Stegun 7.1.26 erf, |abs err| <= 1.5e-7, branch-free
__device__ __forceinline__ float gelu(float v) {
  float ax = fabsf(v) * 0.70710678118654752f;
  float t = 1.0f / fmaf(0.3275911f, ax, 1.0f);
  float p = t * (0.254829592f +
           t * (-0.284496736f +
           t * (1.421413741f +
           t * (-1.453152027f +
           t * 1.061405429f))));
  float e = __expf(-ax * ax);
  float er = copysignf(fmaf(-p, e, 1.0f), v);
  return 0.5f * v * (1.0f + er);
}

// ---------- tables: cosT/sinT fp32 (16x256); ETA hi/lo [32][256]; ET2 hi/lo [256][32] ----------
__global__ __launch_bounds__(256) void k_tables(float* __restrict__ cosT, float* __restrict__ sinT,
                                                ushort* __restrict__ eah, ushort* __restrict__ eal,
                                                ushort* __restrict__ e2h, ushort* __restrict__ e2l) {
  int idx = blockIdx.x * 256 + threadIdx.x;
  const float w = 0.0245436926061702596f;     // 2*pi/256
  if (idx < 4096) {
    int k = idx >> 8, xx = idx & 255;
    int t = (k * xx) & 255;
    float ang = (float)t * w;
    cosT[idx] = cosf(ang);
    sinT[idx] = sinf(ang);
  } else if (idx < 12288) {
    int e = idx - 4096;
    int j = e >> 8, xx = e & 255;
    int k = j >> 1;
    int t = (k * xx) & 255;
    float ang = (float)t * w;
    float val = (j & 1) ? -sinf(ang) : cosf(ang);
    unsigned hi = bf16rne(val);
    unsigned lo = bf16rne(val - bf16tof(hi));
    eah[j * 256 + xx] = (ushort)hi;
    eal[j * 256 + xx] = (ushort)lo;
    e2h[xx * 32 + j] = (ushort)hi;
    e2l[xx * 32 + j] = (ushort)lo;
  }
}

// ---------- wsplit: pre-split w_w (4x64x64) and fc1_w (128x64) ----------
__global__ __launch_bounds__(256) void k_wsplit(const float* __restrict__ ww, const float* __restrict__ w1,
                                                ushort* __restrict__ wh, ushort* __restrict__ wl,
                                                ushort* __restrict__ w1h, ushort* __restrict__ w1l) {
  int idx = blockIdx.x * 256 + threadIdx.x;   // 96*256 = 24576
  if (idx < 16384) {
    float v = ww[idx];
    unsigned hi = bf16rne(v);
    wh[idx] = (ushort)hi;
    wl[idx] = (ushort)bf16rne(v - bf16tof(hi));
  } else if (idx < 24576) {
    int j = idx - 16384;
    float v = w1[j];
    unsigned hi = bf16rne(v);
    w1h[j] = (ushort)hi;
    w1l[j] = (ushort)bf16rne(v - bf16tof(hi));
  }
}

// ---------- fc0: (B,3,H,W) -> h[n][c] split planes ----------
__global__ __launch_bounds__(256) void k_fc0(const float* __restrict__ x, const float* __restrict__ w,
                                             const float* __restrict__ b,
                                             ushort* __restrict__ hh, ushort* __restrict__ hl) {
  int bid = blockIdx.x;                 // 1024 = B*H
  int bb = bid >> 8, y = bid & 255;
  int tx = threadIdx.x;
  __shared__ float ws[192];
  __shared__ float bs[64];
  if (tx < 192) ws[tx] = w[tx];
  if (tx < 64) bs[tx] = b[tx];
  __syncthreads();
  const float* xp = x + ((bb * 3) * 256 + y) * 256 + tx;
  float v0 = xp[0], v1 = xp[HW], v2 = xp[2 * HW];
  size_t n = (size_t)bid * 256 + tx;
#pragma unroll 4
  for (int o4 = 0; o4 < 16; ++o4) {
    ushort4 H, L;
    float vv[4];
#pragma unroll
    for (int q = 0; q < 4; ++q) {
      int o = o4 * 4 + q;
      vv[q] = bs[o] + ws[o * 3] * v0 + ws[o * 3 + 1] * v1 + ws[o * 3 + 2] * v2;
    }
    unsigned h0 = bf16rne(vv[0]), h1 = bf16rne(vv[1]), h2 = bf16rne(vv[2]), h3 = bf16rne(vv[3]);
    H = make_ushort4((ushort)h0, (ushort)h1, (ushort)h2, (ushort)h3);
    L = make_ushort4((ushort)bf16rne(vv[0] - bf16tof(h0)), (ushort)bf16rne(vv[1] - bf16tof(h1)),
                     (ushort)bf16rne(vv[2] - bf16tof(h2)), (ushort)bf16rne(vv[3] - bf16tof(h3)));
    *(ushort4*)&hh[n * 64 + o4 * 4] = H;
    *(ushort4*)&hl[n * 64 + o4 * 4] = L;
  }
}

// ---------- F1 (MFMA + LDS transpose): per (b,y), A1[kspec=32][c=64] = E^T x h_row ----------
// LDS Hs[c][x] with x^=(c&7)<<3 swizzle: staging writes <=4-way, b128 frag reads uniform.
__global__ __launch_bounds__(256) void k_f1(const ushort* __restrict__ hh, const ushort* __restrict__ hl,
                                            const ushort* __restrict__ eah, const ushort* __restrict__ eal,
                                            float* __restrict__ A) {
  int bid = blockIdx.x;                 // 1024 = b*256 + y
  int tid = threadIdx.x;
  __shared__ ushort HsH[64 * 256];      // 32 KB
  __shared__ ushort HsL[64 * 256];      // 32 KB

  // stage: thread (c8 = tid>>5, xi = tid&31) covers 8 c x 8 xq
  {
    int c8 = tid >> 5, xi = tid & 31;
    const ushort* hb = hh + (size_t)bid * 16384;
    const ushort* lb = hl + (size_t)bid * 16384;
#pragma unroll
    for (int xq = 0; xq < 8; ++xq) {
      int x = xq * 32 + xi;
      short8 vh = *(const short8*)&hb[x * 64 + c8 * 8];
      short8 vl = *(const short8*)&lb[x * 64 + c8 * 8];
#pragma unroll
      for (int j = 0; j < 8; ++j) {
        int c = c8 * 8 + j;
        int idx = c * 256 + (x ^ (j << 3));   // (c&7)==j
        HsH[idx] = (ushort)vh[j];
        HsL[idx] = (ushort)vl[j];
      }
    }
  }
  __syncthreads();

  int lane = tid & 63, wave = tid >> 6;
  int lm = lane & 15, lg = lane >> 4;
  int c = wave * 16 + lm;
  int swz = (c & 7) << 3;
  f32x4 acc[2];
  acc[0] = (f32x4){0.f, 0.f, 0.f, 0.f};
  acc[1] = (f32x4){0.f, 0.f, 0.f, 0.f};
#pragma unroll
  for (int kc = 0; kc < 8; ++kc) {
    int xb = (kc * 32 + lg * 8) ^ swz;
    short8 bhv = *(const short8*)&HsH[c * 256 + xb];
    short8 blv = *(const short8*)&HsL[c * 256 + xb];
#pragma unroll
    for (int mi = 0; mi < 2; ++mi) {
      int row = mi * 16 + lm;
      short8 ah = *(const short8*)&eah[row * 256 + kc * 32 + lg * 8];
      short8 al = *(const short8*)&eal[row * 256 + kc * 32 + lg * 8];
      acc[mi] = __builtin_amdgcn_mfma_f32_16x16x32_bf16(ah, bhv, acc[mi], 0, 0, 0);
      acc[mi] = __builtin_amdgcn_mfma_f32_16x16x32_bf16(ah, blv, acc[mi], 0, 0, 0);
      acc[mi] = __builtin_amdgcn_mfma_f32_16x16x32_bf16(al, bhv, acc[mi], 0, 0, 0);
    }
  }
  int b = bid >> 8, y = bid & 255;
  size_t rbase = ((size_t)(b * 64 + c) * 256 + y) * 32;
#pragma unroll
  for (int mi = 0; mi < 2; ++mi)
    *(float4*)&A[rbase + mi * 16 + lg * 4] =
        make_float4(acc[mi][0], acc[mi][1], acc[mi][2], acc[mi][3]);
}

// ---------- F2: col DFT over y, LDS-staged ----------
__global__ __launch_bounds__(256) void k_f2(const float2* __restrict__ A, const float* __restrict__ cosT,
                                            const float* __restrict__ sinT, float2* __restrict__ X) {
  int plane = blockIdx.x;
  int tid = threadIdx.x;
  __shared__ float2 As[256 * 16];
  __shared__ float ct[16 * 257];
  __shared__ float stt[16 * 257];
  const float2* Ap = A + plane * 4096;
#pragma unroll
  for (int rep = 0; rep < 16; ++rep) {
    int flat = rep * 256 + tid;
    As[flat] = Ap[flat];
  }
#pragma unroll
  for (int rep = 0; rep < 16; ++rep) {
    int flat = rep * 256 + tid;
    int ky = flat >> 8, y = flat & 255;
    ct[ky * 257 + y] = cosT[flat];
    stt[ky * 257 + y] = sinT[flat];
  }
  __syncthreads();
  int ky = tid >> 4, kx = tid & 15;
  float xr = 0.f, xi = 0.f;
#pragma unroll 4
  for (int y = 0; y < 256; ++y) {
    float2 a = As[y * 16 + kx];
    float c = ct[ky * 257 + y], s = stt[ky * 257 + y];
    xr += c * a.x + s * a.y;
    xi += c * a.y - s * a.x;
  }
  X[plane * 256 + tid] = make_float2(xr, xi);
}

// ---------- MIX ----------
__global__ __launch_bounds__(256) void k_mix(const float2* __restrict__ X, const float* __restrict__ wr,
                                             const float* __restrict__ wi, float2* __restrict__ Y) {
  int o = blockIdx.x >> 2;
  int mc = blockIdx.x & 3;
  int tid = threadIdx.x;
  int cg = tid >> 6, m2 = tid & 63;
  int m = mc * 64 + m2;
  float yr[4] = {0.f, 0.f, 0.f, 0.f}, yi[4] = {0.f, 0.f, 0.f, 0.f};
#pragma unroll 4
  for (int cc = 0; cc < 16; ++cc) {
    int c = cg * 16 + cc;
    float r = wr[(c * 64 + o) * 256 + m];
    float im = wi[(c * 64 + o) * 256 + m];
#pragma unroll
    for (int b = 0; b < 4; ++b) {
      float2 xv = X[(b * 64 + c) * 256 + m];
      yr[b] += xv.x * r - xv.y * im;
      yi[b] += xv.x * im + xv.y * r;
    }
  }
  __shared__ float2 red[1024];
#pragma unroll
  for (int b = 0; b < 4; ++b) red[cg * 256 + b * 64 + m2] = make_float2(yr[b], yi[b]);
  __syncthreads();
  int b = tid >> 6;
  float sx = 0.f, sy = 0.f;
#pragma unroll
  for (int g2 = 0; g2 < 4; ++g2) {
    float2 v = red[g2 * 256 + b * 64 + m2];
    sx += v.x; sy += v.y;
  }
  Y[(b * 64 + o) * 256 + m] = make_float2(sx, sy);
}

// ---------- INV1: writes g split planes [b*64+o][y][32] ----------
__global__ __launch_bounds__(256) void k_inv1(const float2* __restrict__ Y, const float* __restrict__ cosT,
                                              const float* __restrict__ sinT,
                                              ushort* __restrict__ gh, ushort* __restrict__ gl) {
  int plane = blockIdx.x;               // 256 = B*O
  int y = threadIdx.x;
  __shared__ float2 Ys[256];
  Ys[threadIdx.x] = Y[plane * 256 + threadIdx.x];
  __syncthreads();
  float gr[16], gi[16];
#pragma unroll
  for (int k = 0; k < 16; ++k) { gr[k] = 0.f; gi[k] = 0.f; }
  for (int ky = 0; ky < 16; ++ky) {
    float c = cosT[ky * 256 + y], s = sinT[ky * 256 + y];
#pragma unroll
    for (int kx = 0; kx < 16; ++kx) {
      float2 v = Ys[ky * 16 + kx];
      gr[kx] += c * v.x - s * v.y;
      gi[kx] += c * v.y + s * v.x;
    }
  }
  float val[32];
  const float sc = 1.0f / 65536.0f;
#pragma unroll
  for (int kx = 0; kx < 16; ++kx) {
    float m = (kx == 0) ? sc : 2.0f * sc;
    val[2 * kx] = gr[kx] * m;
    val[2 * kx + 1] = gi[kx] * m;
  }
  size_t gb = ((size_t)plane * 256 + y) * 32;
#pragma unroll
  for (int q = 0; q < 8; ++q) {
    ushort4 H, L;
#pragma unroll
    for (int r = 0; r < 4; ++r) {
      float v = val[q * 4 + r];
      unsigned hi = bf16rne(v);
      ((ushort*)&H)[r] = (ushort)hi;
      ((ushort*)&L)[r] = (ushort)bf16rne(v - bf16tof(hi));
    }
    *(ushort4*)&gh[gb + q * 4] = H;
    *(ushort4*)&gl[gb + q * 4] = L;
  }
}

// ---------- K_LAYER (pure MFMA, ni=1, grid 4096): hout = GELU( [W | g] x [h ; ET] + wb ) ----------
__global__ __launch_bounds__(256) void k_layer(const ushort* __restrict__ hh, const ushort* __restrict__ hl,
                                               const ushort* __restrict__ gh, const ushort* __restrict__ gl,
                                               const ushort* __restrict__ wh, const ushort* __restrict__ wl,
                                               const float* __restrict__ wb,
                                               const ushort* __restrict__ e2h, const ushort* __restrict__ e2l,
                                               ushort* __restrict__ oh, ushort* __restrict__ ol) {
  int bid = blockIdx.x;                 // 4096 = b*1024 + y*4 + xq
  int b = bid >> 10, y = (bid >> 2) & 255, xq = bid & 3;
  int tid = threadIdx.x;
  int lane = tid & 63, wave = tid >> 6;
  int lm = lane & 15, lg = lane >> 4;
  int x = xq * 64 + wave * 16 + lm;
  size_t nb = (size_t)(b * 256 + y) * 256 + x;

  // all B fragments upfront (independent loads)
  short8 bh0 = *(const short8*)&hh[nb * 64 + lg * 8];
  short8 bl0 = *(const short8*)&hl[nb * 64 + lg * 8];
  short8 bh1 = *(const short8*)&hh[nb * 64 + 32 + lg * 8];
  short8 bl1 = *(const short8*)&hl[nb * 64 + 32 + lg * 8];
  short8 eh  = *(const short8*)&e2h[x * 32 + lg * 8];
  short8 el  = *(const short8*)&e2l[x * 32 + lg * 8];

  f32x4 acc[4];
#pragma unroll
  for (int mi = 0; mi < 4; ++mi) acc[mi] = (f32x4){0.f, 0.f, 0.f, 0.f};

#pragma unroll
  for (int mi = 0; mi < 4; ++mi) {
    int o = mi * 16 + lm;
    short8 ah0 = *(const short8*)&wh[o * 64 + lg * 8];
    short8 al0 = *(const short8*)&wl[o * 64 + lg * 8];
    acc[mi] = __builtin_amdgcn_mfma_f32_16x16x32_bf16(ah0, bh0, acc[mi], 0, 0, 0);
    acc[mi] = __builtin_amdgcn_mfma_f32_16x16x32_bf16(ah0, bl0, acc[mi], 0, 0, 0);
    acc[mi] = __builtin_amdgcn_mfma_f32_16x16x32_bf16(al0, bh0, acc[mi], 0, 0, 0);
    short8 ah1 = *(const short8*)&wh[o * 64 + 32 + lg * 8];
    short8 al1 = *(const short8*)&wl[o * 64 + 32 + lg * 8];
    acc[mi] = __builtin_amdgcn_mfma_f32_16x16x32_bf16(ah1, bh1, acc[mi], 0, 0, 0);
    acc[mi] = __builtin_amdgcn_mfma_f32_16x16x32_bf16(ah1, bl1, acc[mi], 0, 0, 0);
    acc[mi] = __builtin_amdgcn_mfma_f32_16x16x32_bf16(al1, bh1, acc[mi], 0, 0, 0);
    size_t ga = ((size_t)(b * 64 + o) * 256 + y) * 32 + lg * 8;
    short8 gah = *(const short8*)&gh[ga];
    short8 gal = *(const short8*)&gl[ga];
    acc[mi] = __builtin_amdgcn_mfma_f32_16x16x32_bf16(gah, eh, acc[mi], 0, 0, 0);
    acc[mi] = __builtin_amdgcn_mfma_f32_16x16x32_bf16(gah, el, acc[mi], 0, 0, 0);
    acc[mi] = __builtin_amdgcn_mfma_f32_16x16x32_bf16(gal, eh, acc[mi], 0, 0, 0);
  }

  // epilogue: bias + GELU + split-store
#pragma unroll
  for (int mi = 0; mi < 4; ++mi) {
    ushort4 H, L;
#pragma unroll
    for (int r = 0; r < 4; ++r) {
      int o = mi * 16 + lg * 4 + r;
      float ge = gelu(acc[mi][r] + wb[o]);
      unsigned hi = bf16rne(ge);
      ((ushort*)&H)[r] = (ushort)hi;
      ((ushort*)&L)[r] = (ushort)bf16rne(ge - bf16tof(hi));
    }
    *(ushort4*)&oh[nb * 64 + mi * 16 + lg * 4] = H;
    *(ushort4*)&ol[nb * 64 + mi * 16 + lg * 4] = L;
  }
}

// ---------- K_FINAL (pure MFMA, ni=1, grid 4096): out = fc2( GELU( fc1(h) ) ) ----------
__global__ __launch_bounds__(256) void k_final(const ushort* __restrict__ hh, const ushort* __restrict__ hl,
                                               const ushort* __restrict__ w1h, const ushort* __restrict__ w1l,
                                               const float* __restrict__ b1, const float* __restrict__ w2,
                                               const float* __restrict__ b2, float* __restrict__ out) {
  int bid = blockIdx.x;                 // 4096 = b*1024 + y*4 + xq
  int b = bid >> 10, y = (bid >> 2) & 255, xq = bid & 3;
  int tid = threadIdx.x;
  int lane = tid & 63, wave = tid >> 6;
  int lm = lane & 15, lg = lane >> 4;
  int x = xq * 64 + wave * 16 + lm;
  size_t nb = (size_t)(b * 256 + y) * 256 + x;

  short8 bh0 = *(const short8*)&hh[nb * 64 + lg * 8];
  short8 bl0 = *(const short8*)&hl[nb * 64 + lg * 8];
  short8 bh1 = *(const short8*)&hh[nb * 64 + 32 + lg * 8];
  short8 bl1 = *(const short8*)&hl[nb * 64 + 32 + lg * 8];

  f32x4 acc[8];
#pragma unroll
  for (int mi = 0; mi < 8; ++mi) acc[mi] = (f32x4){0.f, 0.f, 0.f, 0.f};

#pragma unroll
  for (int mi = 0; mi < 8; ++mi) {
    int j = mi * 16 + lm;
    short8 ah0 = *(const short8*)&w1h[j * 64 + lg * 8];
    short8 al0 = *(const short8*)&w1l[j * 64 + lg * 8];
    acc[mi] = __builtin_amdgcn_mfma_f32_16x16x32_bf16(ah0, bh0, acc[mi], 0, 0, 0);
    acc[mi] = __builtin_amdgcn_mfma_f32_16x16x32_bf16(ah0, bl0, acc[mi], 0, 0, 0);
    acc[mi] = __builtin_amdgcn_mfma_f32_16x16x32_bf16(al0, bh0, acc[mi], 0, 0, 0);
    short8 ah1 = *(const short8*)&w1h[j * 64 + 32 + lg * 8];
    short8 al1 = *(const short8*)&w1l[j * 64 + 32 + lg * 8];
    acc[mi] = __builtin_amdgcn_mfma_f32_16x16x32_bf16(ah1, bh1, acc[mi], 0, 0, 0);
    acc[mi] = __builtin_amdgcn_mfma_f32_16x16x32_bf16(ah1, bl1, acc[mi], 0, 0, 0);
    acc[mi] = __builtin_amdgcn_mfma_f32_16x16x32_bf16(al1, bh1, acc[mi], 0, 0, 0);
  }

  float p = 0.f;
#pragma unroll
  for (int mi = 0; mi < 8; ++mi)
#pragma unroll
    for (int r = 0; r < 4; ++r) {
      int j = mi * 16 + lg * 4 + r;
      p += w2[j] * gelu(acc[mi][r] + b1[j]);
    }
  p += __shfl_xor(p, 16);
  p += __shfl_xor(p, 32);
  if (lg == 0) {
    out[(b * 256 + y) * 256 + x] = p + b2[0];
  }
}

extern "C" void kernel_launch(void* const* d_in, const int* in_sizes, int n_in,
                              void* d_out, int out_size, void* d_ws, size_t ws_size,
                              hipStream_t stream) {
  const float* x       = (const float*)d_in[0];
  const float* fc0_w   = (const float*)d_in[1];
  const float* fc0_b   = (const float*)d_in[2];
  const float* spec_wr = (const float*)d_in[3];
  const float* spec_wi = (const float*)d_in[4];
  const float* w_w     = (const float*)d_in[5];
  const float* w_b     = (const float*)d_in[6];
  const float* fc1_w   = (const float*)d_in[7];
  const float* fc1_b   = (const float*)d_in[8];
  const float* fc2_w   = (const float*)d_in[9];
  const float* fc2_b   = (const float*)d_in[10];
  float* out = (float*)d_out;

  char* ws = (char*)d_ws;
  ushort* h0h  = (ushort*)ws;                              // 33554432 B
  ushort* h0l  = (ushort*)(ws + 33554432);                 // 33554432 B
  ushort* h1h  = (ushort*)(ws + 67108864);                 // 33554432 B
  ushort* h1l  = (ushort*)(ws + 100663296);                // 33554432 B
  float*  A    = (float*)(ws + 134217728);                 // 8388608 B
  ushort* gh   = (ushort*)(ws + 142606336);                // 4194304 B
  ushort* gl   = (ushort*)(ws + 146800640);                // 4194304 B
  float2* X    = (float2*)(ws + 150994944);                // 524288 B
  float2* Y    = (float2*)(ws + 151519232);                // 524288 B
  float*  cosT = (float*)(ws + 152043520);                 // 16384 B
  float*  sinT = (float*)(ws + 152059904);                 // 16384 B
  ushort* eah  = (ushort*)(ws + 152076288);                // 16384 B
  ushort* eal  = (ushort*)(ws + 152092672);                // 16384 B
  ushort* e2h  = (ushort*)(ws + 152109056);                // 16384 B
  ushort* e2l  = (ushort*)(ws + 152125440);                // 16384 B
  ushort* wWh  = (ushort*)(ws + 152141824);                // 32768 B
  ushort* wWl  = (ushort*)(ws + 152174592);                // 32768 B
  ushort* w1h  = (ushort*)(ws + 152207360);                // 16384 B
  ushort* w1l  = (ushort*)(ws + 152223744);                // 16384 B

  k_tables<<<48, 256, 0, stream>>>(cosT, sinT, eah, eal, e2h, e2l);
  k_wsplit<<<96, 256, 0, stream>>>(w_w, fc1_w, wWh, wWl, w1h, w1l);
  k_fc0<<<1024, 256, 0, stream>>>(x, fc0_w, fc0_b, h0h, h0l);
  ushort* hch = h0h; ushort* hcl = h0l;
  ushort* hnh = h1h; ushort* hnl = h1l;
  for (int l = 0; l < 4; ++l) {
    k_f1<<<1024, 256, 0, stream>>>(hch, hcl, eah, eal, A);
    k_f2<<<256, 256, 0, stream>>>((const float2*)A, cosT, sinT, X);
    k_mix<<<256, 256, 0, stream>>>(X, spec_wr + (size_t)l * 1048576, spec_wi + (size_t)l * 1048576, Y);
    k_inv1<<<256, 256, 0, stream>>>(Y, cosT, sinT, gh, gl);
    k_layer<<<4096, 256, 0, stream>>>(hch, hcl, gh, gl, wWh + l * 4096, wWl + l * 4096,
                                      w_b + l * 64, e2h, e2l, hnh, hnl);
    ushort* t;
    t = hch; hch = hnh; hnh = t;
    t = hcl; hcl = hnl; hnl = t;
  }
  k_final<<<4096, 256, 0, stream>>>(hch, hcl, w1h, w1l, fc1_b, fc2_w, fc2_b, out);
}

// Round 9
// 510.189 us; speedup vs baseline: 1.2786x; 1.2786x over previous
//
#include <hip/hip_runtime.h>
#include <math.h>

#define HW 65536

typedef __attribute__((ext_vector_type(8))) short short8;
typedef __attribute__((ext_vector_type(4))) float f32x4;

__device__ __forceinline__ unsigned bf16rne(float f) {
  union { float f; unsigned u; } a; a.f = f;
  return (a.u + 0x7fffu + ((a.u >> 16) & 1u)) >> 16;
}
__device__ __forceinline__ float bf16tof(unsigned h) {
  union { unsigned u; float f; } a; a.u = h << 16;
  return a.f;
}
// fast gelu: Abramowitz-Stegun 7.1.26 erf, |abs err| <= 1.5e-7, branch-free
__device__ __forceinline__ float gelu(float v) {
  float ax = fabsf(v) * 0.70710678118654752f;
  float t = 1.0f / fmaf(0.3275911f, ax, 1.0f);
  float p = t * (0.254829592f +
           t * (-0.284496736f +
           t * (1.421413741f +
           t * (-1.453152027f +
           t * 1.061405429f))));
  float e = __expf(-ax * ax);
  float er = copysignf(fmaf(-p, e, 1.0f), v);
  return 0.5f * v * (1.0f + er);
}

// ---------- tables: cosT/sinT fp32 (16x256); ETA hi/lo [32][256]; ET2 hi/lo [256][32] ----------
__global__ __launch_bounds__(256) void k_tables(float* __restrict__ cosT, float* __restrict__ sinT,
                                                ushort* __restrict__ eah, ushort* __restrict__ eal,
                                                ushort* __restrict__ e2h, ushort* __restrict__ e2l) {
  int idx = blockIdx.x * 256 + threadIdx.x;
  const float w = 0.0245436926061702596f;     // 2*pi/256
  if (idx < 4096) {
    int k = idx >> 8, xx = idx & 255;
    int t = (k * xx) & 255;
    float ang = (float)t * w;
    cosT[idx] = cosf(ang);
    sinT[idx] = sinf(ang);
  } else if (idx < 12288) {
    int e = idx - 4096;
    int j = e >> 8, xx = e & 255;
    int k = j >> 1;
    int t = (k * xx) & 255;
    float ang = (float)t * w;
    float val = (j & 1) ? -sinf(ang) : cosf(ang);
    unsigned hi = bf16rne(val);
    unsigned lo = bf16rne(val - bf16tof(hi));
    eah[j * 256 + xx] = (ushort)hi;
    eal[j * 256 + xx] = (ushort)lo;
    e2h[xx * 32 + j] = (ushort)hi;
    e2l[xx * 32 + j] = (ushort)lo;
  }
}

// ---------- wsplit: pre-split w_w (4x64x64) and fc1_w (128x64) ----------
__global__ __launch_bounds__(256) void k_wsplit(const float* __restrict__ ww, const float* __restrict__ w1,
                                                ushort* __restrict__ wh, ushort* __restrict__ wl,
                                                ushort* __restrict__ w1h, ushort* __restrict__ w1l) {
  int idx = blockIdx.x * 256 + threadIdx.x;   // 96*256 = 24576
  if (idx < 16384) {
    float v = ww[idx];
    unsigned hi = bf16rne(v);
    wh[idx] = (ushort)hi;
    wl[idx] = (ushort)bf16rne(v - bf16tof(hi));
  } else if (idx < 24576) {
    int j = idx - 16384;
    float v = w1[j];
    unsigned hi = bf16rne(v);
    w1h[j] = (ushort)hi;
    w1l[j] = (ushort)bf16rne(v - bf16tof(hi));
  }
}

// ---------- fc0: (B,3,H,W) -> h[n][c] split planes ----------
__global__ __launch_bounds__(256) void k_fc0(const float* __restrict__ x, const float* __restrict__ w,
                                             const float* __restrict__ b,
                                             ushort* __restrict__ hh, ushort* __restrict__ hl) {
  int bid = blockIdx.x;                 // 1024 = B*H
  int bb = bid >> 8, y = bid & 255;
  int tx = threadIdx.x;
  __shared__ float ws[192];
  __shared__ float bs[64];
  if (tx < 192) ws[tx] = w[tx];
  if (tx < 64) bs[tx] = b[tx];
  __syncthreads();
  const float* xp = x + ((bb * 3) * 256 + y) * 256 + tx;
  float v0 = xp[0], v1 = xp[HW], v2 = xp[2 * HW];
  size_t n = (size_t)bid * 256 + tx;
#pragma unroll 4
  for (int o4 = 0; o4 < 16; ++o4) {
    ushort4 H, L;
    float vv[4];
#pragma unroll
    for (int q = 0; q < 4; ++q) {
      int o = o4 * 4 + q;
      vv[q] = bs[o] + ws[o * 3] * v0 + ws[o * 3 + 1] * v1 + ws[o * 3 + 2] * v2;
    }
    unsigned h0 = bf16rne(vv[0]), h1 = bf16rne(vv[1]), h2 = bf16rne(vv[2]), h3 = bf16rne(vv[3]);
    H = make_ushort4((ushort)h0, (ushort)h1, (ushort)h2, (ushort)h3);
    L = make_ushort4((ushort)bf16rne(vv[0] - bf16tof(h0)), (ushort)bf16rne(vv[1] - bf16tof(h1)),
                     (ushort)bf16rne(vv[2] - bf16tof(h2)), (ushort)bf16rne(vv[3] - bf16tof(h3)));
    *(ushort4*)&hh[n * 64 + o4 * 4] = H;
    *(ushort4*)&hl[n * 64 + o4 * 4] = L;
  }
}

// ---------- F1 (MFMA, round-6 gather form): per (b,y), A1[kspec=32][c=64] = E^T x h_row ----------
__global__ __launch_bounds__(256) void k_f1(const ushort* __restrict__ hh, const ushort* __restrict__ hl,
                                            const ushort* __restrict__ eah, const ushort* __restrict__ eal,
                                            float* __restrict__ A) {
  int bid = blockIdx.x;                 // 1024 = b*256 + y
  int tid = threadIdx.x;
  int lane = tid & 63, wave = tid >> 6;
  int lm = lane & 15, lg = lane >> 4;
  int c = wave * 16 + lm;
  const ushort* hb = hh + (size_t)bid * 16384;
  const ushort* lb = hl + (size_t)bid * 16384;
  f32x4 acc[2];
  acc[0] = (f32x4){0.f, 0.f, 0.f, 0.f};
  acc[1] = (f32x4){0.f, 0.f, 0.f, 0.f};
#pragma unroll
  for (int kc = 0; kc < 8; ++kc) {
    int xb = kc * 32 + lg * 8;
    short8 bhv, blv;
#pragma unroll
    for (int i = 0; i < 8; ++i) {
      bhv[i] = (short)hb[(size_t)(xb + i) * 64 + c];
      blv[i] = (short)lb[(size_t)(xb + i) * 64 + c];
    }
#pragma unroll
    for (int mi = 0; mi < 2; ++mi) {
      int row = mi * 16 + lm;
      short8 ah = *(const short8*)&eah[row * 256 + xb];
      short8 al = *(const short8*)&eal[row * 256 + xb];
      acc[mi] = __builtin_amdgcn_mfma_f32_16x16x32_bf16(ah, bhv, acc[mi], 0, 0, 0);
      acc[mi] = __builtin_amdgcn_mfma_f32_16x16x32_bf16(ah, blv, acc[mi], 0, 0, 0);
      acc[mi] = __builtin_amdgcn_mfma_f32_16x16x32_bf16(al, bhv, acc[mi], 0, 0, 0);
    }
  }
  int b = bid >> 8, y = bid & 255;
  size_t rbase = ((size_t)(b * 64 + c) * 256 + y) * 32;
#pragma unroll
  for (int mi = 0; mi < 2; ++mi)
    *(float4*)&A[rbase + mi * 16 + lg * 4] =
        make_float4(acc[mi][0], acc[mi][1], acc[mi][2], acc[mi][3]);
}

// ---------- F2: col DFT over y, LDS-staged ----------
__global__ __launch_bounds__(256) void k_f2(const float2* __restrict__ A, const float* __restrict__ cosT,
                                            const float* __restrict__ sinT, float2* __restrict__ X) {
  int plane = blockIdx.x;
  int tid = threadIdx.x;
  __shared__ float2 As[256 * 16];
  __shared__ float ct[16 * 257];
  __shared__ float stt[16 * 257];
  const float2* Ap = A + plane * 4096;
#pragma unroll
  for (int rep = 0; rep < 16; ++rep) {
    int flat = rep * 256 + tid;
    As[flat] = Ap[flat];
  }
#pragma unroll
  for (int rep = 0; rep < 16; ++rep) {
    int flat = rep * 256 + tid;
    int ky = flat >> 8, y = flat & 255;
    ct[ky * 257 + y] = cosT[flat];
    stt[ky * 257 + y] = sinT[flat];
  }
  __syncthreads();
  int ky = tid >> 4, kx = tid & 15;
  float xr = 0.f, xi = 0.f;
#pragma unroll 4
  for (int y = 0; y < 256; ++y) {
    float2 a = As[y * 16 + kx];
    float c = ct[ky * 257 + y], s = stt[ky * 257 + y];
    xr += c * a.x + s * a.y;
    xi += c * a.y - s * a.x;
  }
  X[plane * 256 + tid] = make_float2(xr, xi);
}

// ---------- MIX ----------
__global__ __launch_bounds__(256) void k_mix(const float2* __restrict__ X, const float* __restrict__ wr,
                                             const float* __restrict__ wi, float2* __restrict__ Y) {
  int o = blockIdx.x >> 2;
  int mc = blockIdx.x & 3;
  int tid = threadIdx.x;
  int cg = tid >> 6, m2 = tid & 63;
  int m = mc * 64 + m2;
  float yr[4] = {0.f, 0.f, 0.f, 0.f}, yi[4] = {0.f, 0.f, 0.f, 0.f};
#pragma unroll 4
  for (int cc = 0; cc < 16; ++cc) {
    int c = cg * 16 + cc;
    float r = wr[(c * 64 + o) * 256 + m];
    float im = wi[(c * 64 + o) * 256 + m];
#pragma unroll
    for (int b = 0; b < 4; ++b) {
      float2 xv = X[(b * 64 + c) * 256 + m];
      yr[b] += xv.x * r - xv.y * im;
      yi[b] += xv.x * im + xv.y * r;
    }
  }
  __shared__ float2 red[1024];
#pragma unroll
  for (int b = 0; b < 4; ++b) red[cg * 256 + b * 64 + m2] = make_float2(yr[b], yi[b]);
  __syncthreads();
  int b = tid >> 6;
  float sx = 0.f, sy = 0.f;
#pragma unroll
  for (int g2 = 0; g2 < 4; ++g2) {
    float2 v = red[g2 * 256 + b * 64 + m2];
    sx += v.x; sy += v.y;
  }
  Y[(b * 64 + o) * 256 + m] = make_float2(sx, sy);
}

// ---------- INV1: writes g split planes [b*64+o][y][32] ----------
__global__ __launch_bounds__(256) void k_inv1(const float2* __restrict__ Y, const float* __restrict__ cosT,
                                              const float* __restrict__ sinT,
                                              ushort* __restrict__ gh, ushort* __restrict__ gl) {
  int plane = blockIdx.x;               // 256 = B*O
  int y = threadIdx.x;
  __shared__ float2 Ys[256];
  Ys[threadIdx.x] = Y[plane * 256 + threadIdx.x];
  __syncthreads();
  float gr[16], gi[16];
#pragma unroll
  for (int k = 0; k < 16; ++k) { gr[k] = 0.f; gi[k] = 0.f; }
  for (int ky = 0; ky < 16; ++ky) {
    float c = cosT[ky * 256 + y], s = sinT[ky * 256 + y];
#pragma unroll
    for (int kx = 0; kx < 16; ++kx) {
      float2 v = Ys[ky * 16 + kx];
      gr[kx] += c * v.x - s * v.y;
      gi[kx] += c * v.y + s * v.x;
    }
  }
  float val[32];
  const float sc = 1.0f / 65536.0f;
#pragma unroll
  for (int kx = 0; kx < 16; ++kx) {
    float m = (kx == 0) ? sc : 2.0f * sc;
    val[2 * kx] = gr[kx] * m;
    val[2 * kx + 1] = gi[kx] * m;
  }
  size_t gb = ((size_t)plane * 256 + y) * 32;
#pragma unroll
  for (int q = 0; q < 8; ++q) {
    ushort4 H, L;
#pragma unroll
    for (int r = 0; r < 4; ++r) {
      float v = val[q * 4 + r];
      unsigned hi = bf16rne(v);
      ((ushort*)&H)[r] = (ushort)hi;
      ((ushort*)&L)[r] = (ushort)bf16rne(v - bf16tof(hi));
    }
    *(ushort4*)&gh[gb + q * 4] = H;
    *(ushort4*)&gl[gb + q * 4] = L;
  }
}

// ---------- K_LAYER: LDS-staged A operands, global B (h). grid 4096 ----------
// LDS rows padded: w stride 72 ushorts (144B, 16B-aligned, 2-way), g/e2 stride 40 (80B).
__global__ __launch_bounds__(256) void k_layer(const ushort* __restrict__ hh, const ushort* __restrict__ hl,
                                               const ushort* __restrict__ gh, const ushort* __restrict__ gl,
                                               const ushort* __restrict__ wh, const ushort* __restrict__ wl,
                                               const float* __restrict__ wb,
                                               const ushort* __restrict__ e2h, const ushort* __restrict__ e2l,
                                               ushort* __restrict__ oh, ushort* __restrict__ ol) {
  int bid = blockIdx.x;                 // 4096 = b*1024 + y*4 + xq
  int b = bid >> 10, y = (bid >> 2) & 255, xq = bid & 3;
  int tid = threadIdx.x;
  int lane = tid & 63, wave = tid >> 6;
  int lm = lane & 15, lg = lane >> 4;
  int x = xq * 64 + wave * 16 + lm;
  size_t nb = (size_t)(b * 256 + y) * 256 + x;

  __shared__ __align__(16) ushort wsH[64 * 72], wsL[64 * 72];
  __shared__ __align__(16) ushort gsH[64 * 40], gsL[64 * 40];
  __shared__ __align__(16) ushort esH[64 * 40], esL[64 * 40];
  __shared__ float wbs[64];

  // stage w: 4096 ushorts/plane, 2 x short8 per thread
#pragma unroll
  for (int rep = 0; rep < 2; ++rep) {
    int flat = rep * 2048 + tid * 8;
    int o = flat >> 6, cc = flat & 63;
    *(short8*)&wsH[o * 72 + cc] = *(const short8*)&wh[flat];
    *(short8*)&wsL[o * 72 + cc] = *(const short8*)&wl[flat];
  }
  // stage g: 2048 ushorts/plane (this (b,y)): thread -> (o = t>>2, i = (t&3)*8)
  {
    int o = tid >> 2, i = (tid & 3) * 8;
    size_t ga = ((size_t)(b * 64 + o) * 256 + y) * 32 + i;
    *(short8*)&gsH[o * 40 + i] = *(const short8*)&gh[ga];
    *(short8*)&gsL[o * 40 + i] = *(const short8*)&gl[ga];
  }
  // stage e2: 64 x-rows of 32 (contiguous 2048 ushorts at xq*2048)
  {
    int xr = tid >> 2, i = (tid & 3) * 8;
    int ea = (xq * 64 + xr) * 32 + i;
    *(short8*)&esH[xr * 40 + i] = *(const short8*)&e2h[ea];
    *(short8*)&esL[xr * 40 + i] = *(const short8*)&e2l[ea];
  }
  if (tid < 64) wbs[tid] = wb[tid];
  __syncthreads();

  // B fragments (h) from global, e2 from LDS
  short8 bh0 = *(const short8*)&hh[nb * 64 + lg * 8];
  short8 bl0 = *(const short8*)&hl[nb * 64 + lg * 8];
  short8 bh1 = *(const short8*)&hh[nb * 64 + 32 + lg * 8];
  short8 bl1 = *(const short8*)&hl[nb * 64 + 32 + lg * 8];
  int xr = wave * 16 + lm;
  short8 eh = *(const short8*)&esH[xr * 40 + lg * 8];
  short8 el = *(const short8*)&esL[xr * 40 + lg * 8];

  f32x4 acc[4];
#pragma unroll
  for (int mi = 0; mi < 4; ++mi) acc[mi] = (f32x4){0.f, 0.f, 0.f, 0.f};

#pragma unroll
  for (int mi = 0; mi < 4; ++mi) {
    int o = mi * 16 + lm;
    short8 ah0 = *(const short8*)&wsH[o * 72 + lg * 8];
    short8 al0 = *(const short8*)&wsL[o * 72 + lg * 8];
    acc[mi] = __builtin_amdgcn_mfma_f32_16x16x32_bf16(ah0, bh0, acc[mi], 0, 0, 0);
    acc[mi] = __builtin_amdgcn_mfma_f32_16x16x32_bf16(ah0, bl0, acc[mi], 0, 0, 0);
    acc[mi] = __builtin_amdgcn_mfma_f32_16x16x32_bf16(al0, bh0, acc[mi], 0, 0, 0);
    short8 ah1 = *(const short8*)&wsH[o * 72 + 32 + lg * 8];
    short8 al1 = *(const short8*)&wsL[o * 72 + 32 + lg * 8];
    acc[mi] = __builtin_amdgcn_mfma_f32_16x16x32_bf16(ah1, bh1, acc[mi], 0, 0, 0);
    acc[mi] = __builtin_amdgcn_mfma_f32_16x16x32_bf16(ah1, bl1, acc[mi], 0, 0, 0);
    acc[mi] = __builtin_amdgcn_mfma_f32_16x16x32_bf16(al1, bh1, acc[mi], 0, 0, 0);
    short8 gah = *(const short8*)&gsH[o * 40 + lg * 8];
    short8 gal = *(const short8*)&gsL[o * 40 + lg * 8];
    acc[mi] = __builtin_amdgcn_mfma_f32_16x16x32_bf16(gah, eh, acc[mi], 0, 0, 0);
    acc[mi] = __builtin_amdgcn_mfma_f32_16x16x32_bf16(gah, el, acc[mi], 0, 0, 0);
    acc[mi] = __builtin_amdgcn_mfma_f32_16x16x32_bf16(gal, eh, acc[mi], 0, 0, 0);
  }

  // epilogue: bias + GELU + split-store
#pragma unroll
  for (int mi = 0; mi < 4; ++mi) {
    ushort4 H, L;
#pragma unroll
    for (int r = 0; r < 4; ++r) {
      int o = mi * 16 + lg * 4 + r;
      float ge = gelu(acc[mi][r] + wbs[o]);
      unsigned hi = bf16rne(ge);
      ((ushort*)&H)[r] = (ushort)hi;
      ((ushort*)&L)[r] = (ushort)bf16rne(ge - bf16tof(hi));
    }
    *(ushort4*)&oh[nb * 64 + mi * 16 + lg * 4] = H;
    *(ushort4*)&ol[nb * 64 + mi * 16 + lg * 4] = L;
  }
}

// ---------- K_FINAL: LDS-staged fc1 weights. grid 4096 ----------
__global__ __launch_bounds__(256) void k_final(const ushort* __restrict__ hh, const ushort* __restrict__ hl,
                                               const ushort* __restrict__ w1h, const ushort* __restrict__ w1l,
                                               const float* __restrict__ b1, const float* __restrict__ w2,
                                               const float* __restrict__ b2, float* __restrict__ out) {
  int bid = blockIdx.x;                 // 4096 = b*1024 + y*4 + xq
  int b = bid >> 10, y = (bid >> 2) & 255, xq = bid & 3;
  int tid = threadIdx.x;
  int lane = tid & 63, wave = tid >> 6;
  int lm = lane & 15, lg = lane >> 4;
  int x = xq * 64 + wave * 16 + lm;
  size_t nb = (size_t)(b * 256 + y) * 256 + x;

  __shared__ __align__(16) ushort w1sH[128 * 72], w1sL[128 * 72];
  __shared__ float b1s[128], w2s[128];

  // stage w1: 8192 ushorts/plane, 4 x short8 per thread
#pragma unroll
  for (int rep = 0; rep < 4; ++rep) {
    int flat = rep * 2048 + tid * 8;
    int j = flat >> 6, cc = flat & 63;
    *(short8*)&w1sH[j * 72 + cc] = *(const short8*)&w1h[flat];
    *(short8*)&w1sL[j * 72 + cc] = *(const short8*)&w1l[flat];
  }
  if (tid < 128) { b1s[tid] = b1[tid]; w2s[tid] = w2[tid]; }
  __syncthreads();

  short8 bh0 = *(const short8*)&hh[nb * 64 + lg * 8];
  short8 bl0 = *(const short8*)&hl[nb * 64 + lg * 8];
  short8 bh1 = *(const short8*)&hh[nb * 64 + 32 + lg * 8];
  short8 bl1 = *(const short8*)&hl[nb * 64 + 32 + lg * 8];

  f32x4 acc[8];
#pragma unroll
  for (int mi = 0; mi < 8; ++mi) acc[mi] = (f32x4){0.f, 0.f, 0.f, 0.f};

#pragma unroll
  for (int mi = 0; mi < 8; ++mi) {
    int j = mi * 16 + lm;
    short8 ah0 = *(const short8*)&w1sH[j * 72 + lg * 8];
    short8 al0 = *(const short8*)&w1sL[j * 72 + lg * 8];
    acc[mi] = __builtin_amdgcn_mfma_f32_16x16x32_bf16(ah0, bh0, acc[mi], 0, 0, 0);
    acc[mi] = __builtin_amdgcn_mfma_f32_16x16x32_bf16(ah0, bl0, acc[mi], 0, 0, 0);
    acc[mi] = __builtin_amdgcn_mfma_f32_16x16x32_bf16(al0, bh0, acc[mi], 0, 0, 0);
    short8 ah1 = *(const short8*)&w1sH[j * 72 + 32 + lg * 8];
    short8 al1 = *(const short8*)&w1sL[j * 72 + 32 + lg * 8];
    acc[mi] = __builtin_amdgcn_mfma_f32_16x16x32_bf16(ah1, bh1, acc[mi], 0, 0, 0);
    acc[mi] = __builtin_amdgcn_mfma_f32_16x16x32_bf16(ah1, bl1, acc[mi], 0, 0, 0);
    acc[mi] = __builtin_amdgcn_mfma_f32_16x16x32_bf16(al1, bh1, acc[mi], 0, 0, 0);
  }

  float p = 0.f;
#pragma unroll
  for (int mi = 0; mi < 8; ++mi)
#pragma unroll
    for (int r = 0; r < 4; ++r) {
      int j = mi * 16 + lg * 4 + r;
      p += w2s[j] * gelu(acc[mi][r] + b1s[j]);
    }
  p += __shfl_xor(p, 16);
  p += __shfl_xor(p, 32);
  if (lg == 0) {
    out[(b * 256 + y) * 256 + x] = p + b2[0];
  }
}

extern "C" void kernel_launch(void* const* d_in, const int* in_sizes, int n_in,
                              void* d_out, int out_size, void* d_ws, size_t ws_size,
                              hipStream_t stream) {
  const float* x       = (const float*)d_in[0];
  const float* fc0_w   = (const float*)d_in[1];
  const float* fc0_b   = (const float*)d_in[2];
  const float* spec_wr = (const float*)d_in[3];
  const float* spec_wi = (const float*)d_in[4];
  const float* w_w     = (const float*)d_in[5];
  const float* w_b     = (const float*)d_in[6];
  const float* fc1_w   = (const float*)d_in[7];
  const float* fc1_b   = (const float*)d_in[8];
  const float* fc2_w   = (const float*)d_in[9];
  const float* fc2_b   = (const float*)d_in[10];
  float* out = (float*)d_out;

  char* ws = (char*)d_ws;
  ushort* h0h  = (ushort*)ws;                              // 33554432 B
  ushort* h0l  = (ushort*)(ws + 33554432);                 // 33554432 B
  ushort* h1h  = (ushort*)(ws + 67108864);                 // 33554432 B
  ushort* h1l  = (ushort*)(ws + 100663296);                // 33554432 B
  float*  A    = (float*)(ws + 134217728);                 // 8388608 B
  ushort* gh   = (ushort*)(ws + 142606336);                // 4194304 B
  ushort* gl   = (ushort*)(ws + 146800640);                // 4194304 B
  float2* X    = (float2*)(ws + 150994944);                // 524288 B
  float2* Y    = (float2*)(ws + 151519232);                // 524288 B
  float*  cosT = (float*)(ws + 152043520);                 // 16384 B
  float*  sinT = (float*)(ws + 152059904);                 // 16384 B
  ushort* eah  = (ushort*)(ws + 152076288);                // 16384 B
  ushort* eal  = (ushort*)(ws + 152092672);                // 16384 B
  ushort* e2h  = (ushort*)(ws + 152109056);                // 16384 B
  ushort* e2l  = (ushort*)(ws + 152125440);                // 16384 B
  ushort* wWh  = (ushort*)(ws + 152141824);                // 32768 B
  ushort* wWl  = (ushort*)(ws + 152174592);                // 32768 B
  ushort* w1h  = (ushort*)(ws + 152207360);                // 16384 B
  ushort* w1l  = (ushort*)(ws + 152223744);                // 16384 B

  k_tables<<<48, 256, 0, stream>>>(cosT, sinT, eah, eal, e2h, e2l);
  k_wsplit<<<96, 256, 0, stream>>>(w_w, fc1_w, wWh, wWl, w1h, w1l);
  k_fc0<<<1024, 256, 0, stream>>>(x, fc0_w, fc0_b, h0h, h0l);
  ushort* hch = h0h; ushort* hcl = h0l;
  ushort* hnh = h1h; ushort* hnl = h1l;
  for (int l = 0; l < 4; ++l) {
    k_f1<<<1024, 256, 0, stream>>>(hch, hcl, eah, eal, A);
    k_f2<<<256, 256, 0, stream>>>((const float2*)A, cosT, sinT, X);
    k_mix<<<256, 256, 0, stream>>>(X, spec_wr + (size_t)l * 1048576, spec_wi + (size_t)l * 1048576, Y);
    k_inv1<<<256, 256, 0, stream>>>(Y, cosT, sinT, gh, gl);
    k_layer<<<4096, 256, 0, stream>>>(hch, hcl, gh, gl, wWh + l * 4096, wWl + l * 4096,
                                      w_b + l * 64, e2h, e2l, hnh, hnl);
    ushort* t;
    t = hch; hch = hnh; hnh = t;
    t = hcl; hcl = hnl; hnl = t;
  }
  k_final<<<4096, 256, 0, stream>>>(hch, hcl, w1h, w1l, fc1_b, fc2_w, fc2_b, out);
}

// Round 10
// 445.860 us; speedup vs baseline: 1.4631x; 1.1443x over previous
//
#include <hip/hip_runtime.h>
#include <math.h>

#define HW 65536

typedef __attribute__((ext_vector_type(8))) short short8;
typedef __attribute__((ext_vector_type(4))) float f32x4;

__device__ __forceinline__ unsigned bf16rne(float f) {
  union { float f; unsigned u; } a; a.f = f;
  return (a.u + 0x7fffu + ((a.u >> 16) & 1u)) >> 16;
}
__device__ __forceinline__ float bf16tof(unsigned h) {
  union { unsigned u; float f; } a; a.u = h << 16;
  return a.f;
}
// fast gelu: Abramowitz-Stegun 7.1.26 erf, |abs err| <= 1.5e-7, branch-free
__device__ __forceinline__ float gelu(float v) {
  float ax = fabsf(v) * 0.70710678118654752f;
  float t = 1.0f / fmaf(0.3275911f, ax, 1.0f);
  float p = t * (0.254829592f +
           t * (-0.284496736f +
           t * (1.421413741f +
           t * (-1.453152027f +
           t * 1.061405429f))));
  float e = __expf(-ax * ax);
  float er = copysignf(fmaf(-p, e, 1.0f), v);
  return 0.5f * v * (1.0f + er);
}

// ---------- tables: cosT/sinT fp32 (16x256); ETA hi/lo [32][256]; ET2 hi/lo [256][32] ----------
__global__ __launch_bounds__(256) void k_tables(float* __restrict__ cosT, float* __restrict__ sinT,
                                                ushort* __restrict__ eah, ushort* __restrict__ eal,
                                                ushort* __restrict__ e2h, ushort* __restrict__ e2l) {
  int idx = blockIdx.x * 256 + threadIdx.x;
  const float w = 0.0245436926061702596f;     // 2*pi/256
  if (idx < 4096) {
    int k = idx >> 8, xx = idx & 255;
    int t = (k * xx) & 255;
    float ang = (float)t * w;
    cosT[idx] = cosf(ang);
    sinT[idx] = sinf(ang);
  } else if (idx < 12288) {
    int e = idx - 4096;
    int j = e >> 8, xx = e & 255;
    int k = j >> 1;
    int t = (k * xx) & 255;
    float ang = (float)t * w;
    float val = (j & 1) ? -sinf(ang) : cosf(ang);
    unsigned hi = bf16rne(val);
    unsigned lo = bf16rne(val - bf16tof(hi));
    eah[j * 256 + xx] = (ushort)hi;
    eal[j * 256 + xx] = (ushort)lo;
    e2h[xx * 32 + j] = (ushort)hi;
    e2l[xx * 32 + j] = (ushort)lo;
  }
}

// ---------- wsplit: pre-split w_w (4x64x64) and fc1_w (128x64) ----------
__global__ __launch_bounds__(256) void k_wsplit(const float* __restrict__ ww, const float* __restrict__ w1,
                                                ushort* __restrict__ wh, ushort* __restrict__ wl,
                                                ushort* __restrict__ w1h, ushort* __restrict__ w1l) {
  int idx = blockIdx.x * 256 + threadIdx.x;   // 96*256 = 24576
  if (idx < 16384) {
    float v = ww[idx];
    unsigned hi = bf16rne(v);
    wh[idx] = (ushort)hi;
    wl[idx] = (ushort)bf16rne(v - bf16tof(hi));
  } else if (idx < 24576) {
    int j = idx - 16384;
    float v = w1[j];
    unsigned hi = bf16rne(v);
    w1h[j] = (ushort)hi;
    w1l[j] = (ushort)bf16rne(v - bf16tof(hi));
  }
}

// ---------- fc0: (B,3,H,W) -> h[n][c] split planes, coalesced 16B stores ----------
__global__ __launch_bounds__(256) void k_fc0(const float* __restrict__ x, const float* __restrict__ w,
                                             const float* __restrict__ b,
                                             ushort* __restrict__ hh, ushort* __restrict__ hl) {
  int bid = blockIdx.x;                 // 1024 = B*H
  int bb = bid >> 8, y = bid & 255;
  int tid = threadIdx.x;
  __shared__ float ws[192];
  __shared__ float bs[64];
  if (tid < 192) ws[tid] = w[tid];
  if (tid < 64) bs[tid] = b[tid];
  __syncthreads();
  const float* xrow = x + ((size_t)(bb * 3) * 256 + y) * 256;
#pragma unroll
  for (int rep = 0; rep < 8; ++rep) {
    int flat = rep * 256 + tid;       // 0..2047: (pixel, 8-c group)
    int p = flat >> 3, q = flat & 7;
    float v0 = xrow[p], v1 = xrow[p + HW], v2 = xrow[p + 2 * HW];
    short8 H, L;
#pragma unroll
    for (int i = 0; i < 8; ++i) {
      int o = q * 8 + i;
      float v = bs[o] + ws[o * 3] * v0 + ws[o * 3 + 1] * v1 + ws[o * 3 + 2] * v2;
      unsigned hi = bf16rne(v);
      H[i] = (short)hi;
      L[i] = (short)bf16rne(v - bf16tof(hi));
    }
    size_t nb = ((size_t)bid * 256 + p) * 64 + q * 8;
    *(short8*)&hh[nb] = H;
    *(short8*)&hl[nb] = L;
  }
}

// ---------- F1 (MFMA gather form): per (b,y), A1[kspec=32][c=64] = E^T x h_row ----------
__global__ __launch_bounds__(256) void k_f1(const ushort* __restrict__ hh, const ushort* __restrict__ hl,
                                            const ushort* __restrict__ eah, const ushort* __restrict__ eal,
                                            float* __restrict__ A) {
  int bid = blockIdx.x;                 // 1024 = b*256 + y
  int tid = threadIdx.x;
  int lane = tid & 63, wave = tid >> 6;
  int lm = lane & 15, lg = lane >> 4;
  int c = wave * 16 + lm;
  const ushort* hb = hh + (size_t)bid * 16384;
  const ushort* lb = hl + (size_t)bid * 16384;
  f32x4 acc[2];
  acc[0] = (f32x4){0.f, 0.f, 0.f, 0.f};
  acc[1] = (f32x4){0.f, 0.f, 0.f, 0.f};
#pragma unroll
  for (int kc = 0; kc < 8; ++kc) {
    int xb = kc * 32 + lg * 8;
    short8 bhv, blv;
#pragma unroll
    for (int i = 0; i < 8; ++i) {
      bhv[i] = (short)hb[(size_t)(xb + i) * 64 + c];
      blv[i] = (short)lb[(size_t)(xb + i) * 64 + c];
    }
#pragma unroll
    for (int mi = 0; mi < 2; ++mi) {
      int row = mi * 16 + lm;
      short8 ah = *(const short8*)&eah[row * 256 + xb];
      short8 al = *(const short8*)&eal[row * 256 + xb];
      acc[mi] = __builtin_amdgcn_mfma_f32_16x16x32_bf16(ah, bhv, acc[mi], 0, 0, 0);
      acc[mi] = __builtin_amdgcn_mfma_f32_16x16x32_bf16(ah, blv, acc[mi], 0, 0, 0);
      acc[mi] = __builtin_amdgcn_mfma_f32_16x16x32_bf16(al, bhv, acc[mi], 0, 0, 0);
    }
  }
  int b = bid >> 8, y = bid & 255;
  size_t rbase = ((size_t)(b * 64 + c) * 256 + y) * 32;
#pragma unroll
  for (int mi = 0; mi < 2; ++mi)
    *(float4*)&A[rbase + mi * 16 + lg * 4] =
        make_float4(acc[mi][0], acc[mi][1], acc[mi][2], acc[mi][3]);
}

// ---------- F2: col DFT over y, LDS-staged ----------
__global__ __launch_bounds__(256) void k_f2(const float2* __restrict__ A, const float* __restrict__ cosT,
                                            const float* __restrict__ sinT, float2* __restrict__ X) {
  int plane = blockIdx.x;
  int tid = threadIdx.x;
  __shared__ float2 As[256 * 16];
  __shared__ float ct[16 * 257];
  __shared__ float stt[16 * 257];
  const float2* Ap = A + plane * 4096;
#pragma unroll
  for (int rep = 0; rep < 16; ++rep) {
    int flat = rep * 256 + tid;
    As[flat] = Ap[flat];
  }
#pragma unroll
  for (int rep = 0; rep < 16; ++rep) {
    int flat = rep * 256 + tid;
    int ky = flat >> 8, y = flat & 255;
    ct[ky * 257 + y] = cosT[flat];
    stt[ky * 257 + y] = sinT[flat];
  }
  __syncthreads();
  int ky = tid >> 4, kx = tid & 15;
  float xr = 0.f, xi = 0.f;
#pragma unroll 4
  for (int y = 0; y < 256; ++y) {
    float2 a = As[y * 16 + kx];
    float c = ct[ky * 257 + y], s = stt[ky * 257 + y];
    xr += c * a.x + s * a.y;
    xi += c * a.y - s * a.x;
  }
  X[plane * 256 + tid] = make_float2(xr, xi);
}

// ---------- MIX ----------
__global__ __launch_bounds__(256) void k_mix(const float2* __restrict__ X, const float* __restrict__ wr,
                                             const float* __restrict__ wi, float2* __restrict__ Y) {
  int o = blockIdx.x >> 2;
  int mc = blockIdx.x & 3;
  int tid = threadIdx.x;
  int cg = tid >> 6, m2 = tid & 63;
  int m = mc * 64 + m2;
  float yr[4] = {0.f, 0.f, 0.f, 0.f}, yi[4] = {0.f, 0.f, 0.f, 0.f};
#pragma unroll 4
  for (int cc = 0; cc < 16; ++cc) {
    int c = cg * 16 + cc;
    float r = wr[(c * 64 + o) * 256 + m];
    float im = wi[(c * 64 + o) * 256 + m];
#pragma unroll
    for (int b = 0; b < 4; ++b) {
      float2 xv = X[(b * 64 + c) * 256 + m];
      yr[b] += xv.x * r - xv.y * im;
      yi[b] += xv.x * im + xv.y * r;
    }
  }
  __shared__ float2 red[1024];
#pragma unroll
  for (int b = 0; b < 4; ++b) red[cg * 256 + b * 64 + m2] = make_float2(yr[b], yi[b]);
  __syncthreads();
  int b = tid >> 6;
  float sx = 0.f, sy = 0.f;
#pragma unroll
  for (int g2 = 0; g2 < 4; ++g2) {
    float2 v = red[g2 * 256 + b * 64 + m2];
    sx += v.x; sy += v.y;
  }
  Y[(b * 64 + o) * 256 + m] = make_float2(sx, sy);
}

// ---------- INV1: writes g split planes [b*64+o][y][32] ----------
__global__ __launch_bounds__(256) void k_inv1(const float2* __restrict__ Y, const float* __restrict__ cosT,
                                              const float* __restrict__ sinT,
                                              ushort* __restrict__ gh, ushort* __restrict__ gl) {
  int plane = blockIdx.x;               // 256 = B*O
  int y = threadIdx.x;
  __shared__ float2 Ys[256];
  Ys[threadIdx.x] = Y[plane * 256 + threadIdx.x];
  __syncthreads();
  float gr[16], gi[16];
#pragma unroll
  for (int k = 0; k < 16; ++k) { gr[k] = 0.f; gi[k] = 0.f; }
  for (int ky = 0; ky < 16; ++ky) {
    float c = cosT[ky * 256 + y], s = sinT[ky * 256 + y];
#pragma unroll
    for (int kx = 0; kx < 16; ++kx) {
      float2 v = Ys[ky * 16 + kx];
      gr[kx] += c * v.x - s * v.y;
      gi[kx] += c * v.y + s * v.x;
    }
  }
  float val[32];
  const float sc = 1.0f / 65536.0f;
#pragma unroll
  for (int kx = 0; kx < 16; ++kx) {
    float m = (kx == 0) ? sc : 2.0f * sc;
    val[2 * kx] = gr[kx] * m;
    val[2 * kx + 1] = gi[kx] * m;
  }
  size_t gb = ((size_t)plane * 256 + y) * 32;
#pragma unroll
  for (int q = 0; q < 8; ++q) {
    ushort4 H, L;
#pragma unroll
    for (int r = 0; r < 4; ++r) {
      float v = val[q * 4 + r];
      unsigned hi = bf16rne(v);
      ((ushort*)&H)[r] = (ushort)hi;
      ((ushort*)&L)[r] = (ushort)bf16rne(v - bf16tof(hi));
    }
    *(ushort4*)&gh[gb + q * 4] = H;
    *(ushort4*)&gl[gb + q * 4] = L;
  }
}

// ---------- K_LAYER: LDS-staged A operands, global B (h), coalesced epilogue. grid 4096 ----------
__global__ __launch_bounds__(256) void k_layer(const ushort* __restrict__ hh, const ushort* __restrict__ hl,
                                               const ushort* __restrict__ gh, const ushort* __restrict__ gl,
                                               const ushort* __restrict__ wh, const ushort* __restrict__ wl,
                                               const float* __restrict__ wb,
                                               const ushort* __restrict__ e2h, const ushort* __restrict__ e2l,
                                               ushort* __restrict__ oh, ushort* __restrict__ ol) {
  int bid = blockIdx.x;                 // 4096 = b*1024 + y*4 + xq
  int b = bid >> 10, y = (bid >> 2) & 255, xq = bid & 3;
  int tid = threadIdx.x;
  int lane = tid & 63, wave = tid >> 6;
  int lm = lane & 15, lg = lane >> 4;
  int x = xq * 64 + wave * 16 + lm;
  size_t nb = (size_t)(b * 256 + y) * 256 + x;

  __shared__ __align__(16) ushort wsH[64 * 72], wsL[64 * 72];
  __shared__ __align__(16) ushort gsH[64 * 40], gsL[64 * 40];
  __shared__ __align__(16) ushort esH[64 * 40], esL[64 * 40];
  __shared__ float wbs[64];

  // stage w: 4096 ushorts/plane, 2 x short8 per thread
#pragma unroll
  for (int rep = 0; rep < 2; ++rep) {
    int flat = rep * 2048 + tid * 8;
    int o = flat >> 6, cc = flat & 63;
    *(short8*)&wsH[o * 72 + cc] = *(const short8*)&wh[flat];
    *(short8*)&wsL[o * 72 + cc] = *(const short8*)&wl[flat];
  }
  // stage g: this (b,y): thread -> (o = t>>2, i = (t&3)*8)
  {
    int o = tid >> 2, i = (tid & 3) * 8;
    size_t ga = ((size_t)(b * 64 + o) * 256 + y) * 32 + i;
    *(short8*)&gsH[o * 40 + i] = *(const short8*)&gh[ga];
    *(short8*)&gsL[o * 40 + i] = *(const short8*)&gl[ga];
  }
  // stage e2: 64 x-rows of 32 (contiguous at xq*2048)
  {
    int xr = tid >> 2, i = (tid & 3) * 8;
    int ea = (xq * 64 + xr) * 32 + i;
    *(short8*)&esH[xr * 40 + i] = *(const short8*)&e2h[ea];
    *(short8*)&esL[xr * 40 + i] = *(const short8*)&e2l[ea];
  }
  if (tid < 64) wbs[tid] = wb[tid];
  __syncthreads();

  // B fragments (h) from global, e2 from LDS
  short8 bh0 = *(const short8*)&hh[nb * 64 + lg * 8];
  short8 bl0 = *(const short8*)&hl[nb * 64 + lg * 8];
  short8 bh1 = *(const short8*)&hh[nb * 64 + 32 + lg * 8];
  short8 bl1 = *(const short8*)&hl[nb * 64 + 32 + lg * 8];
  int xr = wave * 16 + lm;
  short8 eh = *(const short8*)&esH[xr * 40 + lg * 8];
  short8 el = *(const short8*)&esL[xr * 40 + lg * 8];

  f32x4 acc[4];
#pragma unroll
  for (int mi = 0; mi < 4; ++mi) acc[mi] = (f32x4){0.f, 0.f, 0.f, 0.f};

#pragma unroll
  for (int mi = 0; mi < 4; ++mi) {
    int o = mi * 16 + lm;
    short8 ah0 = *(const short8*)&wsH[o * 72 + lg * 8];
    short8 al0 = *(const short8*)&wsL[o * 72 + lg * 8];
    acc[mi] = __builtin_amdgcn_mfma_f32_16x16x32_bf16(ah0, bh0, acc[mi], 0, 0, 0);
    acc[mi] = __builtin_amdgcn_mfma_f32_16x16x32_bf16(ah0, bl0, acc[mi], 0, 0, 0);
    acc[mi] = __builtin_amdgcn_mfma_f32_16x16x32_bf16(al0, bh0, acc[mi], 0, 0, 0);
    short8 ah1 = *(const short8*)&wsH[o * 72 + 32 + lg * 8];
    short8 al1 = *(const short8*)&wsL[o * 72 + 32 + lg * 8];
    acc[mi] = __builtin_amdgcn_mfma_f32_16x16x32_bf16(ah1, bh1, acc[mi], 0, 0, 0);
    acc[mi] = __builtin_amdgcn_mfma_f32_16x16x32_bf16(ah1, bl1, acc[mi], 0, 0, 0);
    acc[mi] = __builtin_amdgcn_mfma_f32_16x16x32_bf16(al1, bh1, acc[mi], 0, 0, 0);
    short8 gah = *(const short8*)&gsH[o * 40 + lg * 8];
    short8 gal = *(const short8*)&gsL[o * 40 + lg * 8];
    acc[mi] = __builtin_amdgcn_mfma_f32_16x16x32_bf16(gah, eh, acc[mi], 0, 0, 0);
    acc[mi] = __builtin_amdgcn_mfma_f32_16x16x32_bf16(gah, el, acc[mi], 0, 0, 0);
    acc[mi] = __builtin_amdgcn_mfma_f32_16x16x32_bf16(gal, eh, acc[mi], 0, 0, 0);
  }

  // epilogue: bias + GELU + split -> LDS (reuse wsH/wsL as [x][o] stride 72) -> coalesced stores
  __syncthreads();
  int xl = wave * 16 + lm;
#pragma unroll
  for (int mi = 0; mi < 4; ++mi) {
    ushort4 H, L;
#pragma unroll
    for (int r = 0; r < 4; ++r) {
      int o = mi * 16 + lg * 4 + r;
      float ge = gelu(acc[mi][r] + wbs[o]);
      unsigned hi = bf16rne(ge);
      ((ushort*)&H)[r] = (ushort)hi;
      ((ushort*)&L)[r] = (ushort)bf16rne(ge - bf16tof(hi));
    }
    *(ushort4*)&wsH[xl * 72 + mi * 16 + lg * 4] = H;
    *(ushort4*)&wsL[xl * 72 + mi * 16 + lg * 4] = L;
  }
  __syncthreads();
  size_t rowbase = (size_t)(b * 256 + y) * 256 + xq * 64;
#pragma unroll
  for (int rep = 0; rep < 2; ++rep) {
    int ch = rep * 256 + tid;         // 0..511: (pixel, 16B chunk)
    int p = ch >> 3, off = (ch & 7) * 8;
    short8 vH = *(const short8*)&wsH[p * 72 + off];
    short8 vL = *(const short8*)&wsL[p * 72 + off];
    *(short8*)&oh[(rowbase + p) * 64 + off] = vH;
    *(short8*)&ol[(rowbase + p) * 64 + off] = vL;
  }
}

// ---------- K_FINAL: LDS-staged fc1 weights. grid 4096 ----------
__global__ __launch_bounds__(256) void k_final(const ushort* __restrict__ hh, const ushort* __restrict__ hl,
                                               const ushort* __restrict__ w1h, const ushort* __restrict__ w1l,
                                               const float* __restrict__ b1, const float* __restrict__ w2,
                                               const float* __restrict__ b2, float* __restrict__ out) {
  int bid = blockIdx.x;                 // 4096 = b*1024 + y*4 + xq
  int b = bid >> 10, y = (bid >> 2) & 255, xq = bid & 3;
  int tid = threadIdx.x;
  int lane = tid & 63, wave = tid >> 6;
  int lm = lane & 15, lg = lane >> 4;
  int x = xq * 64 + wave * 16 + lm;
  size_t nb = (size_t)(b * 256 + y) * 256 + x;

  __shared__ __align__(16) ushort w1sH[128 * 72], w1sL[128 * 72];
  __shared__ float b1s[128], w2s[128];

  // stage w1: 8192 ushorts/plane, 4 x short8 per thread
#pragma unroll
  for (int rep = 0; rep < 4; ++rep) {
    int flat = rep * 2048 + tid * 8;
    int j = flat >> 6, cc = flat & 63;
    *(short8*)&w1sH[j * 72 + cc] = *(const short8*)&w1h[flat];
    *(short8*)&w1sL[j * 72 + cc] = *(const short8*)&w1l[flat];
  }
  if (tid < 128) { b1s[tid] = b1[tid]; w2s[tid] = w2[tid]; }
  __syncthreads();

  short8 bh0 = *(const short8*)&hh[nb * 64 + lg * 8];
  short8 bl0 = *(const short8*)&hl[nb * 64 + lg * 8];
  short8 bh1 = *(const short8*)&hh[nb * 64 + 32 + lg * 8];
  short8 bl1 = *(const short8*)&hl[nb * 64 + 32 + lg * 8];

  f32x4 acc[8];
#pragma unroll
  for (int mi = 0; mi < 8; ++mi) acc[mi] = (f32x4){0.f, 0.f, 0.f, 0.f};

#pragma unroll
  for (int mi = 0; mi < 8; ++mi) {
    int j = mi * 16 + lm;
    short8 ah0 = *(const short8*)&w1sH[j * 72 + lg * 8];
    short8 al0 = *(const short8*)&w1sL[j * 72 + lg * 8];
    acc[mi] = __builtin_amdgcn_mfma_f32_16x16x32_bf16(ah0, bh0, acc[mi], 0, 0, 0);
    acc[mi] = __builtin_amdgcn_mfma_f32_16x16x32_bf16(ah0, bl0, acc[mi], 0, 0, 0);
    acc[mi] = __builtin_amdgcn_mfma_f32_16x16x32_bf16(al0, bh0, acc[mi], 0, 0, 0);
    short8 ah1 = *(const short8*)&w1sH[j * 72 + 32 + lg * 8];
    short8 al1 = *(const short8*)&w1sL[j * 72 + 32 + lg * 8];
    acc[mi] = __builtin_amdgcn_mfma_f32_16x16x32_bf16(ah1, bh1, acc[mi], 0, 0, 0);
    acc[mi] = __builtin_amdgcn_mfma_f32_16x16x32_bf16(ah1, bl1, acc[mi], 0, 0, 0);
    acc[mi] = __builtin_amdgcn_mfma_f32_16x16x32_bf16(al1, bh1, acc[mi], 0, 0, 0);
  }

  float p = 0.f;
#pragma unroll
  for (int mi = 0; mi < 8; ++mi)
#pragma unroll
    for (int r = 0; r < 4; ++r) {
      int j = mi * 16 + lg * 4 + r;
      p += w2s[j] * gelu(acc[mi][r] + b1s[j]);
    }
  p += __shfl_xor(p, 16);
  p += __shfl_xor(p, 32);
  if (lg == 0) {
    out[(b * 256 + y) * 256 + x] = p + b2[0];
  }
}

extern "C" void kernel_launch(void* const* d_in, const int* in_sizes, int n_in,
                              void* d_out, int out_size, void* d_ws, size_t ws_size,
                              hipStream_t stream) {
  const float* x       = (const float*)d_in[0];
  const float* fc0_w   = (const float*)d_in[1];
  const float* fc0_b   = (const float*)d_in[2];
  const float* spec_wr = (const float*)d_in[3];
  const float* spec_wi = (const float*)d_in[4];
  const float* w_w     = (const float*)d_in[5];
  const float* w_b     = (const float*)d_in[6];
  const float* fc1_w   = (const float*)d_in[7];
  const float* fc1_b   = (const float*)d_in[8];
  const float* fc2_w   = (const float*)d_in[9];
  const float* fc2_b   = (const float*)d_in[10];
  float* out = (float*)d_out;

  char* ws = (char*)d_ws;
  ushort* h0h  = (ushort*)ws;                              // 33554432 B
  ushort* h0l  = (ushort*)(ws + 33554432);                 // 33554432 B
  ushort* h1h  = (ushort*)(ws + 67108864);                 // 33554432 B
  ushort* h1l  = (ushort*)(ws + 100663296);                // 33554432 B
  float*  A    = (float*)(ws + 134217728);                 // 8388608 B
  ushort* gh   = (ushort*)(ws + 142606336);                // 4194304 B
  ushort* gl   = (ushort*)(ws + 146800640);                // 4194304 B
  float2* X    = (float2*)(ws + 150994944);                // 524288 B
  float2* Y    = (float2*)(ws + 151519232);                // 524288 B
  float*  cosT = (float*)(ws + 152043520);                 // 16384 B
  float*  sinT = (float*)(ws + 152059904);                 // 16384 B
  ushort* eah  = (ushort*)(ws + 152076288);                // 16384 B
  ushort* eal  = (ushort*)(ws + 152092672);                // 16384 B
  ushort* e2h  = (ushort*)(ws + 152109056);                // 16384 B
  ushort* e2l  = (ushort*)(ws + 152125440);                // 16384 B
  ushort* wWh  = (ushort*)(ws + 152141824);                // 32768 B
  ushort* wWl  = (ushort*)(ws + 152174592);                // 32768 B
  ushort* w1h  = (ushort*)(ws + 152207360);                // 16384 B
  ushort* w1l  = (ushort*)(ws + 152223744);                // 16384 B

  k_tables<<<48, 256, 0, stream>>>(cosT, sinT, eah, eal, e2h, e2l);
  k_wsplit<<<96, 256, 0, stream>>>(w_w, fc1_w, wWh, wWl, w1h, w1l);
  k_fc0<<<1024, 256, 0, stream>>>(x, fc0_w, fc0_b, h0h, h0l);
  ushort* hch = h0h; ushort* hcl = h0l;
  ushort* hnh = h1h; ushort* hnl = h1l;
  for (int l = 0; l < 4; ++l) {
    k_f1<<<1024, 256, 0, stream>>>(hch, hcl, eah, eal, A);
    k_f2<<<256, 256, 0, stream>>>((const float2*)A, cosT, sinT, X);
    k_mix<<<256, 256, 0, stream>>>(X, spec_wr + (size_t)l * 1048576, spec_wi + (size_t)l * 1048576, Y);
    k_inv1<<<256, 256, 0, stream>>>(Y, cosT, sinT, gh, gl);
    k_layer<<<4096, 256, 0, stream>>>(hch, hcl, gh, gl, wWh + l * 4096, wWl + l * 4096,
                                      w_b + l * 64, e2h, e2l, hnh, hnl);
    ushort* t;
    t = hch; hch = hnh; hnh = t;
    t = hcl; hcl = hnl; hnl = t;
  }
  k_final<<<4096, 256, 0, stream>>>(hch, hcl, w1h, w1l, fc1_b, fc2_w, fc2_b, out);
}

// Round 11
// 416.868 us; speedup vs baseline: 1.5648x; 1.0695x over previous
//
#include <hip/hip_runtime.h>
#include <math.h>

#define HW 65536

typedef __attribute__((ext_vector_type(8))) short short8;
typedef __attribute__((ext_vector_type(4))) float f32x4;

__device__ __forceinline__ unsigned bf16rne(float f) {
  union { float f; unsigned u; } a; a.f = f;
  return (a.u + 0x7fffu + ((a.u >> 16) & 1u)) >> 16;
}
__device__ __forceinline__ float bf16tof(unsigned h) {
  union { unsigned u; float f; } a; a.u = h << 16;
  return a.f;
}
// fast gelu: Abramowitz-Stegun 7.1.26 erf, |abs err| <= 1.5e-7, branch-free
__device__ __forceinline__ float gelu(float v) {
  float ax = fabsf(v) * 0.70710678118654752f;
  float t = 1.0f / fmaf(0.3275911f, ax, 1.0f);
  float p = t * (0.254829592f +
           t * (-0.284496736f +
           t * (1.421413741f +
           t * (-1.453152027f +
           t * 1.061405429f))));
  float e = __expf(-ax * ax);
  float er = copysignf(fmaf(-p, e, 1.0f), v);
  return 0.5f * v * (1.0f + er);
}

// ---------- tables ----------
__global__ __launch_bounds__(256) void k_tables(float* __restrict__ cosT, float* __restrict__ sinT,
                                                ushort* __restrict__ eah, ushort* __restrict__ eal,
                                                ushort* __restrict__ e2h, ushort* __restrict__ e2l) {
  int idx = blockIdx.x * 256 + threadIdx.x;
  const float w = 0.0245436926061702596f;     // 2*pi/256
  if (idx < 4096) {
    int k = idx >> 8, xx = idx & 255;
    int t = (k * xx) & 255;
    float ang = (float)t * w;
    cosT[idx] = cosf(ang);
    sinT[idx] = sinf(ang);
  } else if (idx < 12288) {
    int e = idx - 4096;
    int j = e >> 8, xx = e & 255;
    int k = j >> 1;
    int t = (k * xx) & 255;
    float ang = (float)t * w;
    float val = (j & 1) ? -sinf(ang) : cosf(ang);
    unsigned hi = bf16rne(val);
    unsigned lo = bf16rne(val - bf16tof(hi));
    eah[j * 256 + xx] = (ushort)hi;
    eal[j * 256 + xx] = (ushort)lo;
    e2h[xx * 32 + j] = (ushort)hi;
    e2l[xx * 32 + j] = (ushort)lo;
  }
}

// ---------- wsplit ----------
__global__ __launch_bounds__(256) void k_wsplit(const float* __restrict__ ww, const float* __restrict__ w1,
                                                ushort* __restrict__ wh, ushort* __restrict__ wl,
                                                ushort* __restrict__ w1h, ushort* __restrict__ w1l) {
  int idx = blockIdx.x * 256 + threadIdx.x;   // 96*256 = 24576
  if (idx < 16384) {
    float v = ww[idx];
    unsigned hi = bf16rne(v);
    wh[idx] = (ushort)hi;
    wl[idx] = (ushort)bf16rne(v - bf16tof(hi));
  } else if (idx < 24576) {
    int j = idx - 16384;
    float v = w1[j];
    unsigned hi = bf16rne(v);
    w1h[j] = (ushort)hi;
    w1l[j] = (ushort)bf16rne(v - bf16tof(hi));
  }
}

// ---------- fc0: h planes + fused full-row x-DFT (one wave per quarter) ----------
// A2 layout: A2[((b*64+c)*256+y)*128 + xq*32 + s], s = lg*8 + mtile*4 + r (perm of ks).
__global__ __launch_bounds__(256) void k_fc0(const float* __restrict__ x, const float* __restrict__ w,
                                             const float* __restrict__ b,
                                             const ushort* __restrict__ eah, const ushort* __restrict__ eal,
                                             ushort* __restrict__ hh, ushort* __restrict__ hl,
                                             float* __restrict__ A2) {
  int bid = blockIdx.x;                 // 1024 = B*H
  int bb = bid >> 8, y = bid & 255;
  int tid = threadIdx.x;
  __shared__ float ws[192];
  __shared__ float bs[64];
  __shared__ __align__(16) ushort XsH[256 * 66], XsL[256 * 66];
  if (tid < 192) ws[tid] = w[tid];
  if (tid < 64) bs[tid] = b[tid];
  __syncthreads();
  const float* xrow = x + ((size_t)(bb * 3) * 256 + y) * 256;
#pragma unroll
  for (int rep = 0; rep < 8; ++rep) {
    int flat = rep * 256 + tid;       // (pixel p, 8-c group q)
    int p = flat >> 3, q = flat & 7;
    float v0 = xrow[p], v1 = xrow[p + HW], v2 = xrow[p + 2 * HW];
    short8 H, L;
#pragma unroll
    for (int i = 0; i < 8; ++i) {
      int o = q * 8 + i;
      float v = bs[o] + ws[o * 3] * v0 + ws[o * 3 + 1] * v1 + ws[o * 3 + 2] * v2;
      unsigned hi = bf16rne(v);
      H[i] = (short)hi;
      L[i] = (short)bf16rne(v - bf16tof(hi));
    }
    size_t nb = ((size_t)bid * 256 + p) * 64 + q * 8;
    *(short8*)&hh[nb] = H;
    *(short8*)&hl[nb] = L;
    *(short8*)&XsH[p * 66 + q * 8] = H;
    *(short8*)&XsL[p * 66 + q * 8] = L;
  }
  __syncthreads();
  // fused F1: wave wv handles x-quarter wv
  int lane = tid & 63, wv = tid >> 6;
  int lm = lane & 15, lg = lane >> 4;
#pragma unroll
  for (int ntile = 0; ntile < 4; ++ntile) {
    f32x4 dacc[2];
    dacc[0] = (f32x4){0.f, 0.f, 0.f, 0.f};
    dacc[1] = (f32x4){0.f, 0.f, 0.f, 0.f};
#pragma unroll
    for (int kstep = 0; kstep < 2; ++kstep) {
      int x0 = wv * 64 + kstep * 32 + lg * 8;
      short8 bh, bl;
#pragma unroll
      for (int i = 0; i < 8; ++i) {
        int idx = (x0 + i) * 66 + ntile * 16 + lm;
        bh[i] = (short)XsH[idx];
        bl[i] = (short)XsL[idx];
      }
#pragma unroll
      for (int mtile = 0; mtile < 2; ++mtile) {
        short8 ah = *(const short8*)&eah[(mtile * 16 + lm) * 256 + x0];
        short8 al = *(const short8*)&eal[(mtile * 16 + lm) * 256 + x0];
        dacc[mtile] = __builtin_amdgcn_mfma_f32_16x16x32_bf16(ah, bh, dacc[mtile], 0, 0, 0);
        dacc[mtile] = __builtin_amdgcn_mfma_f32_16x16x32_bf16(ah, bl, dacc[mtile], 0, 0, 0);
        dacc[mtile] = __builtin_amdgcn_mfma_f32_16x16x32_bf16(al, bh, dacc[mtile], 0, 0, 0);
      }
    }
    int c = ntile * 16 + lm;
    size_t row = ((size_t)(bb * 64 + c) * 256 + y) * 128 + wv * 32 + lg * 8;
    *(float4*)&A2[row] = make_float4(dacc[0][0], dacc[0][1], dacc[0][2], dacc[0][3]);
    *(float4*)&A2[row + 4] = make_float4(dacc[1][0], dacc[1][1], dacc[1][2], dacc[1][3]);
  }
}

// ---------- F2: col DFT over y; sums 4 x-quarter partials from A2 during staging ----------
__global__ __launch_bounds__(256) void k_f2(const float* __restrict__ A2, const float* __restrict__ cosT,
                                            const float* __restrict__ sinT, float2* __restrict__ X) {
  int plane = blockIdx.x;               // 256 = B*C
  int tid = threadIdx.x;
  __shared__ float2 As[256 * 16];
  __shared__ float ct[16 * 257];
  __shared__ float stt[16 * 257];
  const float* Ap = A2 + (size_t)plane * 256 * 128;
#pragma unroll
  for (int rep = 0; rep < 16; ++rep) {
    int flat = rep * 256 + tid;
    int y = flat >> 4, j = flat & 15;
    int twoj = 2 * j;
    int s = ((twoj >> 2) & 3) * 8 + (twoj >> 4) * 4 + (twoj & 3);   // perm: ks -> stored idx
    float2 v = make_float2(0.f, 0.f);
#pragma unroll
    for (int q = 0; q < 4; ++q) {
      float2 a = *(const float2*)&Ap[y * 128 + q * 32 + s];
      v.x += a.x; v.y += a.y;
    }
    As[y * 16 + j] = v;
  }
#pragma unroll
  for (int rep = 0; rep < 16; ++rep) {
    int flat = rep * 256 + tid;
    int ky = flat >> 8, y = flat & 255;
    ct[ky * 257 + y] = cosT[flat];
    stt[ky * 257 + y] = sinT[flat];
  }
  __syncthreads();
  int ky = tid >> 4, kx = tid & 15;
  float xr = 0.f, xi = 0.f;
#pragma unroll 4
  for (int y = 0; y < 256; ++y) {
    float2 a = As[y * 16 + kx];
    float c = ct[ky * 257 + y], s = stt[ky * 257 + y];
    xr += c * a.x + s * a.y;
    xi += c * a.y - s * a.x;
  }
  X[plane * 256 + tid] = make_float2(xr, xi);
}

// ---------- MIX ----------
__global__ __launch_bounds__(256) void k_mix(const float2* __restrict__ X, const float* __restrict__ wr,
                                             const float* __restrict__ wi, float2* __restrict__ Y) {
  int o = blockIdx.x >> 2;
  int mc = blockIdx.x & 3;
  int tid = threadIdx.x;
  int cg = tid >> 6, m2 = tid & 63;
  int m = mc * 64 + m2;
  float yr[4] = {0.f, 0.f, 0.f, 0.f}, yi[4] = {0.f, 0.f, 0.f, 0.f};
#pragma unroll 4
  for (int cc = 0; cc < 16; ++cc) {
    int c = cg * 16 + cc;
    float r = wr[(c * 64 + o) * 256 + m];
    float im = wi[(c * 64 + o) * 256 + m];
#pragma unroll
    for (int b = 0; b < 4; ++b) {
      float2 xv = X[(b * 64 + c) * 256 + m];
      yr[b] += xv.x * r - xv.y * im;
      yi[b] += xv.x * im + xv.y * r;
    }
  }
  __shared__ float2 red[1024];
#pragma unroll
  for (int b = 0; b < 4; ++b) red[cg * 256 + b * 64 + m2] = make_float2(yr[b], yi[b]);
  __syncthreads();
  int b = tid >> 6;
  float sx = 0.f, sy = 0.f;
#pragma unroll
  for (int g2 = 0; g2 < 4; ++g2) {
    float2 v = red[g2 * 256 + b * 64 + m2];
    sx += v.x; sy += v.y;
  }
  Y[(b * 64 + o) * 256 + m] = make_float2(sx, sy);
}

// ---------- INV1: writes g split planes [b*64+o][y][32] ----------
__global__ __launch_bounds__(256) void k_inv1(const float2* __restrict__ Y, const float* __restrict__ cosT,
                                              const float* __restrict__ sinT,
                                              ushort* __restrict__ gh, ushort* __restrict__ gl) {
  int plane = blockIdx.x;               // 256 = B*O
  int y = threadIdx.x;
  __shared__ float2 Ys[256];
  Ys[threadIdx.x] = Y[plane * 256 + threadIdx.x];
  __syncthreads();
  float gr[16], gi[16];
#pragma unroll
  for (int k = 0; k < 16; ++k) { gr[k] = 0.f; gi[k] = 0.f; }
  for (int ky = 0; ky < 16; ++ky) {
    float c = cosT[ky * 256 + y], s = sinT[ky * 256 + y];
#pragma unroll
    for (int kx = 0; kx < 16; ++kx) {
      float2 v = Ys[ky * 16 + kx];
      gr[kx] += c * v.x - s * v.y;
      gi[kx] += c * v.y + s * v.x;
    }
  }
  float val[32];
  const float sc = 1.0f / 65536.0f;
#pragma unroll
  for (int kx = 0; kx < 16; ++kx) {
    float m = (kx == 0) ? sc : 2.0f * sc;
    val[2 * kx] = gr[kx] * m;
    val[2 * kx + 1] = gi[kx] * m;
  }
  size_t gb = ((size_t)plane * 256 + y) * 32;
#pragma unroll
  for (int q = 0; q < 8; ++q) {
    ushort4 H, L;
#pragma unroll
    for (int r = 0; r < 4; ++r) {
      float v = val[q * 4 + r];
      unsigned hi = bf16rne(v);
      ((ushort*)&H)[r] = (ushort)hi;
      ((ushort*)&L)[r] = (ushort)bf16rne(v - bf16tof(hi));
    }
    *(ushort4*)&gh[gb + q * 4] = H;
    *(ushort4*)&gl[gb + q * 4] = L;
  }
}

// ---------- K_LAYER: GEMM + coalesced epilogue + fused partial x-DFT of h_next ----------
__global__ __launch_bounds__(256) void k_layer(const ushort* __restrict__ hh, const ushort* __restrict__ hl,
                                               const ushort* __restrict__ gh, const ushort* __restrict__ gl,
                                               const ushort* __restrict__ wh, const ushort* __restrict__ wl,
                                               const float* __restrict__ wb,
                                               const ushort* __restrict__ e2h, const ushort* __restrict__ e2l,
                                               const ushort* __restrict__ eah, const ushort* __restrict__ eal,
                                               ushort* __restrict__ oh, ushort* __restrict__ ol,
                                               float* __restrict__ A2, int do_dft) {
  int bid = blockIdx.x;                 // 4096 = b*1024 + y*4 + xq
  int b = bid >> 10, y = (bid >> 2) & 255, xq = bid & 3;
  int tid = threadIdx.x;
  int lane = tid & 63, wave = tid >> 6;
  int lm = lane & 15, lg = lane >> 4;
  int x = xq * 64 + wave * 16 + lm;
  size_t nb = (size_t)(b * 256 + y) * 256 + x;

  __shared__ __align__(16) ushort wsH[64 * 72], wsL[64 * 72];
  __shared__ __align__(16) ushort gsH[64 * 40], gsL[64 * 40];
  __shared__ __align__(16) ushort esH[64 * 40], esL[64 * 40];
  __shared__ float wbs[64];

  // stage w
#pragma unroll
  for (int rep = 0; rep < 2; ++rep) {
    int flat = rep * 2048 + tid * 8;
    int o = flat >> 6, cc = flat & 63;
    *(short8*)&wsH[o * 72 + cc] = *(const short8*)&wh[flat];
    *(short8*)&wsL[o * 72 + cc] = *(const short8*)&wl[flat];
  }
  // stage g
  {
    int o = tid >> 2, i = (tid & 3) * 8;
    size_t ga = ((size_t)(b * 64 + o) * 256 + y) * 32 + i;
    *(short8*)&gsH[o * 40 + i] = *(const short8*)&gh[ga];
    *(short8*)&gsL[o * 40 + i] = *(const short8*)&gl[ga];
  }
  // stage e2
  {
    int xr = tid >> 2, i = (tid & 3) * 8;
    int ea = (xq * 64 + xr) * 32 + i;
    *(short8*)&esH[xr * 40 + i] = *(const short8*)&e2h[ea];
    *(short8*)&esL[xr * 40 + i] = *(const short8*)&e2l[ea];
  }
  if (tid < 64) wbs[tid] = wb[tid];
  __syncthreads();

  short8 bh0 = *(const short8*)&hh[nb * 64 + lg * 8];
  short8 bl0 = *(const short8*)&hl[nb * 64 + lg * 8];
  short8 bh1 = *(const short8*)&hh[nb * 64 + 32 + lg * 8];
  short8 bl1 = *(const short8*)&hl[nb * 64 + 32 + lg * 8];
  int xr = wave * 16 + lm;
  short8 eh = *(const short8*)&esH[xr * 40 + lg * 8];
  short8 el = *(const short8*)&esL[xr * 40 + lg * 8];

  f32x4 acc[4];
#pragma unroll
  for (int mi = 0; mi < 4; ++mi) acc[mi] = (f32x4){0.f, 0.f, 0.f, 0.f};

#pragma unroll
  for (int mi = 0; mi < 4; ++mi) {
    int o = mi * 16 + lm;
    short8 ah0 = *(const short8*)&wsH[o * 72 + lg * 8];
    short8 al0 = *(const short8*)&wsL[o * 72 + lg * 8];
    acc[mi] = __builtin_amdgcn_mfma_f32_16x16x32_bf16(ah0, bh0, acc[mi], 0, 0, 0);
    acc[mi] = __builtin_amdgcn_mfma_f32_16x16x32_bf16(ah0, bl0, acc[mi], 0, 0, 0);
    acc[mi] = __builtin_amdgcn_mfma_f32_16x16x32_bf16(al0, bh0, acc[mi], 0, 0, 0);
    short8 ah1 = *(const short8*)&wsH[o * 72 + 32 + lg * 8];
    short8 al1 = *(const short8*)&wsL[o * 72 + 32 + lg * 8];
    acc[mi] = __builtin_amdgcn_mfma_f32_16x16x32_bf16(ah1, bh1, acc[mi], 0, 0, 0);
    acc[mi] = __builtin_amdgcn_mfma_f32_16x16x32_bf16(ah1, bl1, acc[mi], 0, 0, 0);
    acc[mi] = __builtin_amdgcn_mfma_f32_16x16x32_bf16(al1, bh1, acc[mi], 0, 0, 0);
    short8 gah = *(const short8*)&gsH[o * 40 + lg * 8];
    short8 gal = *(const short8*)&gsL[o * 40 + lg * 8];
    acc[mi] = __builtin_amdgcn_mfma_f32_16x16x32_bf16(gah, eh, acc[mi], 0, 0, 0);
    acc[mi] = __builtin_amdgcn_mfma_f32_16x16x32_bf16(gah, el, acc[mi], 0, 0, 0);
    acc[mi] = __builtin_amdgcn_mfma_f32_16x16x32_bf16(gal, eh, acc[mi], 0, 0, 0);
  }

  // epilogue: bias + GELU + split -> LDS [x][o] stride 66 (reuse wsH/wsL) -> coalesced stores
  __syncthreads();
  int xl = wave * 16 + lm;
#pragma unroll
  for (int mi = 0; mi < 4; ++mi) {
    ushort4 H, L;
#pragma unroll
    for (int r = 0; r < 4; ++r) {
      int o = mi * 16 + lg * 4 + r;
      float ge = gelu(acc[mi][r] + wbs[o]);
      unsigned hi = bf16rne(ge);
      ((ushort*)&H)[r] = (ushort)hi;
      ((ushort*)&L)[r] = (ushort)bf16rne(ge - bf16tof(hi));
    }
    *(ushort4*)&wsH[xl * 66 + mi * 16 + lg * 4] = H;
    *(ushort4*)&wsL[xl * 66 + mi * 16 + lg * 4] = L;
  }
  __syncthreads();
  size_t rowbase = (size_t)(b * 256 + y) * 256 + xq * 64;
#pragma unroll
  for (int rep = 0; rep < 2; ++rep) {
    int ch = rep * 256 + tid;         // (pixel p, 16B chunk)
    int p = ch >> 3, off = (ch & 7) * 8;
    short8 vH = *(const short8*)&wsH[p * 66 + off];
    short8 vL = *(const short8*)&wsL[p * 66 + off];
    *(short8*)&oh[(rowbase + p) * 64 + off] = vH;
    *(short8*)&ol[(rowbase + p) * 64 + off] = vL;
  }

  // fused partial x-DFT of h_next over this quarter: wave = ntile (c 16-slice)
  if (do_dft) {
    f32x4 dacc[2];
    dacc[0] = (f32x4){0.f, 0.f, 0.f, 0.f};
    dacc[1] = (f32x4){0.f, 0.f, 0.f, 0.f};
#pragma unroll
    for (int kstep = 0; kstep < 2; ++kstep) {
      int xls = kstep * 32 + lg * 8;
      short8 bh, bl;
#pragma unroll
      for (int i = 0; i < 8; ++i) {
        int idx = (xls + i) * 66 + wave * 16 + lm;
        bh[i] = (short)wsH[idx];
        bl[i] = (short)wsL[idx];
      }
      int x0g = xq * 64 + xls;
#pragma unroll
      for (int mtile = 0; mtile < 2; ++mtile) {
        short8 ah = *(const short8*)&eah[(mtile * 16 + lm) * 256 + x0g];
        short8 al = *(const short8*)&eal[(mtile * 16 + lm) * 256 + x0g];
        dacc[mtile] = __builtin_amdgcn_mfma_f32_16x16x32_bf16(ah, bh, dacc[mtile], 0, 0, 0);
        dacc[mtile] = __builtin_amdgcn_mfma_f32_16x16x32_bf16(ah, bl, dacc[mtile], 0, 0, 0);
        dacc[mtile] = __builtin_amdgcn_mfma_f32_16x16x32_bf16(al, bh, dacc[mtile], 0, 0, 0);
      }
    }
    int c = wave * 16 + lm;
    size_t row = ((size_t)(b * 64 + c) * 256 + y) * 128 + xq * 32 + lg * 8;
    *(float4*)&A2[row] = make_float4(dacc[0][0], dacc[0][1], dacc[0][2], dacc[0][3]);
    *(float4*)&A2[row + 4] = make_float4(dacc[1][0], dacc[1][1], dacc[1][2], dacc[1][3]);
  }
}

// ---------- K_FINAL: LDS-staged fc1 weights. grid 4096 ----------
__global__ __launch_bounds__(256) void k_final(const ushort* __restrict__ hh, const ushort* __restrict__ hl,
                                               const ushort* __restrict__ w1h, const ushort* __restrict__ w1l,
                                               const float* __restrict__ b1, const float* __restrict__ w2,
                                               const float* __restrict__ b2, float* __restrict__ out) {
  int bid = blockIdx.x;                 // 4096 = b*1024 + y*4 + xq
  int b = bid >> 10, y = (bid >> 2) & 255, xq = bid & 3;
  int tid = threadIdx.x;
  int lane = tid & 63, wave = tid >> 6;
  int lm = lane & 15, lg = lane >> 4;
  int x = xq * 64 + wave * 16 + lm;
  size_t nb = (size_t)(b * 256 + y) * 256 + x;

  __shared__ __align__(16) ushort w1sH[128 * 72], w1sL[128 * 72];
  __shared__ float b1s[128], w2s[128];

#pragma unroll
  for (int rep = 0; rep < 4; ++rep) {
    int flat = rep * 2048 + tid * 8;
    int j = flat >> 6, cc = flat & 63;
    *(short8*)&w1sH[j * 72 + cc] = *(const short8*)&w1h[flat];
    *(short8*)&w1sL[j * 72 + cc] = *(const short8*)&w1l[flat];
  }
  if (tid < 128) { b1s[tid] = b1[tid]; w2s[tid] = w2[tid]; }
  __syncthreads();

  short8 bh0 = *(const short8*)&hh[nb * 64 + lg * 8];
  short8 bl0 = *(const short8*)&hl[nb * 64 + lg * 8];
  short8 bh1 = *(const short8*)&hh[nb * 64 + 32 + lg * 8];
  short8 bl1 = *(const short8*)&hl[nb * 64 + 32 + lg * 8];

  f32x4 acc[8];
#pragma unroll
  for (int mi = 0; mi < 8; ++mi) acc[mi] = (f32x4){0.f, 0.f, 0.f, 0.f};

#pragma unroll
  for (int mi = 0; mi < 8; ++mi) {
    int j = mi * 16 + lm;
    short8 ah0 = *(const short8*)&w1sH[j * 72 + lg * 8];
    short8 al0 = *(const short8*)&w1sL[j * 72 + lg * 8];
    acc[mi] = __builtin_amdgcn_mfma_f32_16x16x32_bf16(ah0, bh0, acc[mi], 0, 0, 0);
    acc[mi] = __builtin_amdgcn_mfma_f32_16x16x32_bf16(ah0, bl0, acc[mi], 0, 0, 0);
    acc[mi] = __builtin_amdgcn_mfma_f32_16x16x32_bf16(al0, bh0, acc[mi], 0, 0, 0);
    short8 ah1 = *(const short8*)&w1sH[j * 72 + 32 + lg * 8];
    short8 al1 = *(const short8*)&w1sL[j * 72 + 32 + lg * 8];
    acc[mi] = __builtin_amdgcn_mfma_f32_16x16x32_bf16(ah1, bh1, acc[mi], 0, 0, 0);
    acc[mi] = __builtin_amdgcn_mfma_f32_16x16x32_bf16(ah1, bl1, acc[mi], 0, 0, 0);
    acc[mi] = __builtin_amdgcn_mfma_f32_16x16x32_bf16(al1, bh1, acc[mi], 0, 0, 0);
  }

  float p = 0.f;
#pragma unroll
  for (int mi = 0; mi < 8; ++mi)
#pragma unroll
    for (int r = 0; r < 4; ++r) {
      int j = mi * 16 + lg * 4 + r;
      p += w2s[j] * gelu(acc[mi][r] + b1s[j]);
    }
  p += __shfl_xor(p, 16);
  p += __shfl_xor(p, 32);
  if (lg == 0) {
    out[(b * 256 + y) * 256 + x] = p + b2[0];
  }
}

extern "C" void kernel_launch(void* const* d_in, const int* in_sizes, int n_in,
                              void* d_out, int out_size, void* d_ws, size_t ws_size,
                              hipStream_t stream) {
  const float* x       = (const float*)d_in[0];
  const float* fc0_w   = (const float*)d_in[1];
  const float* fc0_b   = (const float*)d_in[2];
  const float* spec_wr = (const float*)d_in[3];
  const float* spec_wi = (const float*)d_in[4];
  const float* w_w     = (const float*)d_in[5];
  const float* w_b     = (const float*)d_in[6];
  const float* fc1_w   = (const float*)d_in[7];
  const float* fc1_b   = (const float*)d_in[8];
  const float* fc2_w   = (const float*)d_in[9];
  const float* fc2_b   = (const float*)d_in[10];
  float* out = (float*)d_out;

  char* ws = (char*)d_ws;
  ushort* h0h  = (ushort*)ws;                              // 33554432 B
  ushort* h0l  = (ushort*)(ws + 33554432);                 // 33554432 B
  ushort* h1h  = (ushort*)(ws + 67108864);                 // 33554432 B
  ushort* h1l  = (ushort*)(ws + 100663296);                // 33554432 B
  float*  A2   = (float*)(ws + 134217728);                 // 33554432 B
  ushort* gh   = (ushort*)(ws + 167772160);                // 4194304 B
  ushort* gl   = (ushort*)(ws + 171966464);                // 4194304 B
  float2* X    = (float2*)(ws + 176160768);                // 524288 B
  float2* Y    = (float2*)(ws + 176685056);                // 524288 B
  float*  cosT = (float*)(ws + 177209344);                 // 16384 B
  float*  sinT = (float*)(ws + 177225728);                 // 16384 B
  ushort* eah  = (ushort*)(ws + 177242112);                // 16384 B
  ushort* eal  = (ushort*)(ws + 177258496);                // 16384 B
  ushort* e2h  = (ushort*)(ws + 177274880);                // 16384 B
  ushort* e2l  = (ushort*)(ws + 177291264);                // 16384 B
  ushort* wWh  = (ushort*)(ws + 177307648);                // 32768 B
  ushort* wWl  = (ushort*)(ws + 177340416);                // 32768 B
  ushort* w1h  = (ushort*)(ws + 177373184);                // 16384 B
  ushort* w1l  = (ushort*)(ws + 177389568);                // 16384 B

  k_tables<<<48, 256, 0, stream>>>(cosT, sinT, eah, eal, e2h, e2l);
  k_wsplit<<<96, 256, 0, stream>>>(w_w, fc1_w, wWh, wWl, w1h, w1l);
  k_fc0<<<1024, 256, 0, stream>>>(x, fc0_w, fc0_b, eah, eal, h0h, h0l, A2);
  ushort* hch = h0h; ushort* hcl = h0l;
  ushort* hnh = h1h; ushort* hnl = h1l;
  for (int l = 0; l < 4; ++l) {
    k_f2<<<256, 256, 0, stream>>>(A2, cosT, sinT, X);
    k_mix<<<256, 256, 0, stream>>>(X, spec_wr + (size_t)l * 1048576, spec_wi + (size_t)l * 1048576, Y);
    k_inv1<<<256, 256, 0, stream>>>(Y, cosT, sinT, gh, gl);
    k_layer<<<4096, 256, 0, stream>>>(hch, hcl, gh, gl, wWh + l * 4096, wWl + l * 4096,
                                      w_b + l * 64, e2h, e2l, eah, eal, hnh, hnl, A2, (l < 3) ? 1 : 0);
    ushort* t;
    t = hch; hch = hnh; hnh = t;
    t = hcl; hcl = hnl; hnl = t;
  }
  k_final<<<4096, 256, 0, stream>>>(hch, hcl, w1h, w1l, fc1_b, fc2_w, fc2_b, out);
}

// Round 12
// 356.163 us; speedup vs baseline: 1.8316x; 1.1704x over previous
//
#include <hip/hip_runtime.h>
#include <math.h>

#define HW 65536

typedef __attribute__((ext_vector_type(8))) short short8;
typedef __attribute__((ext_vector_type(4))) float f32x4;

__device__ __forceinline__ unsigned bf16rne(float f) {
  union { float f; unsigned u; } a; a.f = f;
  return (a.u + 0x7fffu + ((a.u >> 16) & 1u)) >> 16;
}
__device__ __forceinline__ float bf16tof(unsigned h) {
  union { unsigned u; float f; } a; a.u = h << 16;
  return a.f;
}
// fast gelu: Abramowitz-Stegun 7.1.26 erf, |abs err| <= 1.5e-7, branch-free
__device__ __forceinline__ float gelu(float v) {
  float ax = fabsf(v) * 0.70710678118654752f;
  float t = 1.0f / fmaf(0.3275911f, ax, 1.0f);
  float p = t * (0.254829592f +
           t * (-0.284496736f +
           t * (1.421413741f +
           t * (-1.453152027f +
           t * 1.061405429f))));
  float e = __expf(-ax * ax);
  float er = copysignf(fmaf(-p, e, 1.0f), v);
  return 0.5f * v * (1.0f + er);
}

// ---------- tables + weight pre-split (merged) ----------
__global__ __launch_bounds__(256) void k_tables(float* __restrict__ cosT, float* __restrict__ sinT,
                                                ushort* __restrict__ eah, ushort* __restrict__ eal,
                                                ushort* __restrict__ e2h, ushort* __restrict__ e2l,
                                                const float* __restrict__ ww, const float* __restrict__ w1,
                                                ushort* __restrict__ wh, ushort* __restrict__ wl,
                                                ushort* __restrict__ w1h, ushort* __restrict__ w1l) {
  int idx = blockIdx.x * 256 + threadIdx.x;   // 144*256 = 36864
  const float w = 0.0245436926061702596f;     // 2*pi/256
  if (idx < 4096) {
    int k = idx >> 8, xx = idx & 255;
    int t = (k * xx) & 255;
    float ang = (float)t * w;
    cosT[idx] = cosf(ang);
    sinT[idx] = sinf(ang);
  } else if (idx < 12288) {
    int e = idx - 4096;
    int j = e >> 8, xx = e & 255;
    int k = j >> 1;
    int t = (k * xx) & 255;
    float ang = (float)t * w;
    float val = (j & 1) ? -sinf(ang) : cosf(ang);
    unsigned hi = bf16rne(val);
    unsigned lo = bf16rne(val - bf16tof(hi));
    eah[j * 256 + xx] = (ushort)hi;
    eal[j * 256 + xx] = (ushort)lo;
    e2h[xx * 32 + j] = (ushort)hi;
    e2l[xx * 32 + j] = (ushort)lo;
  } else if (idx < 28672) {
    int j = idx - 12288;
    float v = ww[j];
    unsigned hi = bf16rne(v);
    wh[j] = (ushort)hi;
    wl[j] = (ushort)bf16rne(v - bf16tof(hi));
  } else {
    int j = idx - 28672;                      // 8192
    float v = w1[j];
    unsigned hi = bf16rne(v);
    w1h[j] = (ushort)hi;
    w1l[j] = (ushort)bf16rne(v - bf16tof(hi));
  }
}

// ---------- fc0: h plane (bf16) + fused full-row x-DFT ----------
// A2 layout: A2[((b*64+c)*256+y)*128 + xq*32 + s], s = lg*8 + mtile*4 + r.
__global__ __launch_bounds__(256) void k_fc0(const float* __restrict__ x, const float* __restrict__ w,
                                             const float* __restrict__ b,
                                             const ushort* __restrict__ eah, const ushort* __restrict__ eal,
                                             ushort* __restrict__ hh, float* __restrict__ A2) {
  int bid = blockIdx.x;                 // 1024 = B*H
  int bb = bid >> 8, y = bid & 255;
  int tid = threadIdx.x;
  __shared__ float ws[192];
  __shared__ float bs[64];
  __shared__ __align__(16) ushort XsH[256 * 66];
  if (tid < 192) ws[tid] = w[tid];
  if (tid < 64) bs[tid] = b[tid];
  __syncthreads();
  const float* xrow = x + ((size_t)(bb * 3) * 256 + y) * 256;
#pragma unroll
  for (int rep = 0; rep < 8; ++rep) {
    int flat = rep * 256 + tid;       // (pixel p, 8-c group q)
    int p = flat >> 3, q = flat & 7;
    float v0 = xrow[p], v1 = xrow[p + HW], v2 = xrow[p + 2 * HW];
    short8 H;
#pragma unroll
    for (int i = 0; i < 8; ++i) {
      int o = q * 8 + i;
      float v = bs[o] + ws[o * 3] * v0 + ws[o * 3 + 1] * v1 + ws[o * 3 + 2] * v2;
      H[i] = (short)bf16rne(v);
    }
    size_t nb = ((size_t)bid * 256 + p) * 64 + q * 8;
    *(short8*)&hh[nb] = H;
    *(short8*)&XsH[p * 66 + q * 8] = H;
  }
  __syncthreads();
  // fused F1: wave wv handles x-quarter wv
  int lane = tid & 63, wv = tid >> 6;
  int lm = lane & 15, lg = lane >> 4;
#pragma unroll
  for (int ntile = 0; ntile < 4; ++ntile) {
    f32x4 dacc[2];
    dacc[0] = (f32x4){0.f, 0.f, 0.f, 0.f};
    dacc[1] = (f32x4){0.f, 0.f, 0.f, 0.f};
#pragma unroll
    for (int kstep = 0; kstep < 2; ++kstep) {
      int x0 = wv * 64 + kstep * 32 + lg * 8;
      short8 bh;
#pragma unroll
      for (int i = 0; i < 8; ++i) {
        bh[i] = (short)XsH[(x0 + i) * 66 + ntile * 16 + lm];
      }
#pragma unroll
      for (int mtile = 0; mtile < 2; ++mtile) {
        short8 ah = *(const short8*)&eah[(mtile * 16 + lm) * 256 + x0];
        short8 al = *(const short8*)&eal[(mtile * 16 + lm) * 256 + x0];
        dacc[mtile] = __builtin_amdgcn_mfma_f32_16x16x32_bf16(ah, bh, dacc[mtile], 0, 0, 0);
        dacc[mtile] = __builtin_amdgcn_mfma_f32_16x16x32_bf16(al, bh, dacc[mtile], 0, 0, 0);
      }
    }
    int c = ntile * 16 + lm;
    size_t row = ((size_t)(bb * 64 + c) * 256 + y) * 128 + wv * 32 + lg * 8;
    *(float4*)&A2[row] = make_float4(dacc[0][0], dacc[0][1], dacc[0][2], dacc[0][3]);
    *(float4*)&A2[row + 4] = make_float4(dacc[1][0], dacc[1][1], dacc[1][2], dacc[1][3]);
  }
}

// ---------- F2: col DFT over y; sums 4 x-quarter partials from A2 during staging ----------
__global__ __launch_bounds__(256) void k_f2(const float* __restrict__ A2, const float* __restrict__ cosT,
                                            const float* __restrict__ sinT, float2* __restrict__ X) {
  int plane = blockIdx.x;               // 256 = B*C
  int tid = threadIdx.x;
  __shared__ float2 As[256 * 16];
  __shared__ float ct[16 * 257];
  __shared__ float stt[16 * 257];
  const float* Ap = A2 + (size_t)plane * 256 * 128;
#pragma unroll
  for (int rep = 0; rep < 16; ++rep) {
    int flat = rep * 256 + tid;
    int y = flat >> 4, j = flat & 15;
    int twoj = 2 * j;
    int s = ((twoj >> 2) & 3) * 8 + (twoj >> 4) * 4 + (twoj & 3);   // perm: ks -> stored idx
    float2 v = make_float2(0.f, 0.f);
#pragma unroll
    for (int q = 0; q < 4; ++q) {
      float2 a = *(const float2*)&Ap[y * 128 + q * 32 + s];
      v.x += a.x; v.y += a.y;
    }
    As[y * 16 + j] = v;
  }
#pragma unroll
  for (int rep = 0; rep < 16; ++rep) {
    int flat = rep * 256 + tid;
    int ky = flat >> 8, y = flat & 255;
    ct[ky * 257 + y] = cosT[flat];
    stt[ky * 257 + y] = sinT[flat];
  }
  __syncthreads();
  int ky = tid >> 4, kx = tid & 15;
  float xr = 0.f, xi = 0.f;
#pragma unroll 4
  for (int y = 0; y < 256; ++y) {
    float2 a = As[y * 16 + kx];
    float c = ct[ky * 257 + y], s = stt[ky * 257 + y];
    xr += c * a.x + s * a.y;
    xi += c * a.y - s * a.x;
  }
  X[plane * 256 + tid] = make_float2(xr, xi);
}

// ---------- MIX ----------
__global__ __launch_bounds__(256) void k_mix(const float2* __restrict__ X, const float* __restrict__ wr,
                                             const float* __restrict__ wi, float2* __restrict__ Y) {
  int o = blockIdx.x >> 2;
  int mc = blockIdx.x & 3;
  int tid = threadIdx.x;
  int cg = tid >> 6, m2 = tid & 63;
  int m = mc * 64 + m2;
  float yr[4] = {0.f, 0.f, 0.f, 0.f}, yi[4] = {0.f, 0.f, 0.f, 0.f};
#pragma unroll 4
  for (int cc = 0; cc < 16; ++cc) {
    int c = cg * 16 + cc;
    float r = wr[(c * 64 + o) * 256 + m];
    float im = wi[(c * 64 + o) * 256 + m];
#pragma unroll
    for (int b = 0; b < 4; ++b) {
      float2 xv = X[(b * 64 + c) * 256 + m];
      yr[b] += xv.x * r - xv.y * im;
      yi[b] += xv.x * im + xv.y * r;
    }
  }
  __shared__ float2 red[1024];
#pragma unroll
  for (int b = 0; b < 4; ++b) red[cg * 256 + b * 64 + m2] = make_float2(yr[b], yi[b]);
  __syncthreads();
  int b = tid >> 6;
  float sx = 0.f, sy = 0.f;
#pragma unroll
  for (int g2 = 0; g2 < 4; ++g2) {
    float2 v = red[g2 * 256 + b * 64 + m2];
    sx += v.x; sy += v.y;
  }
  Y[(b * 64 + o) * 256 + m] = make_float2(sx, sy);
}

// ---------- INV1: writes g split planes [b*64+o][y][32] ----------
__global__ __launch_bounds__(256) void k_inv1(const float2* __restrict__ Y, const float* __restrict__ cosT,
                                              const float* __restrict__ sinT,
                                              ushort* __restrict__ gh, ushort* __restrict__ gl) {
  int plane = blockIdx.x;               // 256 = B*O
  int y = threadIdx.x;
  __shared__ float2 Ys[256];
  Ys[threadIdx.x] = Y[plane * 256 + threadIdx.x];
  __syncthreads();
  float gr[16], gi[16];
#pragma unroll
  for (int k = 0; k < 16; ++k) { gr[k] = 0.f; gi[k] = 0.f; }
  for (int ky = 0; ky < 16; ++ky) {
    float c = cosT[ky * 256 + y], s = sinT[ky * 256 + y];
#pragma unroll
    for (int kx = 0; kx < 16; ++kx) {
      float2 v = Ys[ky * 16 + kx];
      gr[kx] += c * v.x - s * v.y;
      gi[kx] += c * v.y + s * v.x;
    }
  }
  float val[32];
  const float sc = 1.0f / 65536.0f;
#pragma unroll
  for (int kx = 0; kx < 16; ++kx) {
    float m = (kx == 0) ? sc : 2.0f * sc;
    val[2 * kx] = gr[kx] * m;
    val[2 * kx + 1] = gi[kx] * m;
  }
  size_t gb = ((size_t)plane * 256 + y) * 32;
#pragma unroll
  for (int q = 0; q < 8; ++q) {
    ushort4 H, L;
#pragma unroll
    for (int r = 0; r < 4; ++r) {
      float v = val[q * 4 + r];
      unsigned hi = bf16rne(v);
      ((ushort*)&H)[r] = (ushort)hi;
      ((ushort*)&L)[r] = (ushort)bf16rne(v - bf16tof(hi));
    }
    *(ushort4*)&gh[gb + q * 4] = H;
    *(ushort4*)&gl[gb + q * 4] = L;
  }
}

// ---------- K_LAYER: GEMM + coalesced epilogue + fused partial x-DFT of h_next ----------
__global__ __launch_bounds__(256) void k_layer(const ushort* __restrict__ hh,
                                               const ushort* __restrict__ gh, const ushort* __restrict__ gl,
                                               const ushort* __restrict__ wh, const ushort* __restrict__ wl,
                                               const float* __restrict__ wb,
                                               const ushort* __restrict__ e2h, const ushort* __restrict__ e2l,
                                               const ushort* __restrict__ eah, const ushort* __restrict__ eal,
                                               ushort* __restrict__ oh,
                                               float* __restrict__ A2, int do_dft) {
  int bid = blockIdx.x;                 // 4096 = b*1024 + y*4 + xq
  int b = bid >> 10, y = (bid >> 2) & 255, xq = bid & 3;
  int tid = threadIdx.x;
  int lane = tid & 63, wave = tid >> 6;
  int lm = lane & 15, lg = lane >> 4;
  int x = xq * 64 + wave * 16 + lm;
  size_t nb = (size_t)(b * 256 + y) * 256 + x;

  __shared__ __align__(16) ushort wsH[64 * 72], wsL[64 * 72];
  __shared__ __align__(16) ushort gsH[64 * 40], gsL[64 * 40];
  __shared__ __align__(16) ushort esH[64 * 40], esL[64 * 40];
  __shared__ float wbs[64];

  // stage w
#pragma unroll
  for (int rep = 0; rep < 2; ++rep) {
    int flat = rep * 2048 + tid * 8;
    int o = flat >> 6, cc = flat & 63;
    *(short8*)&wsH[o * 72 + cc] = *(const short8*)&wh[flat];
    *(short8*)&wsL[o * 72 + cc] = *(const short8*)&wl[flat];
  }
  // stage g
  {
    int o = tid >> 2, i = (tid & 3) * 8;
    size_t ga = ((size_t)(b * 64 + o) * 256 + y) * 32 + i;
    *(short8*)&gsH[o * 40 + i] = *(const short8*)&gh[ga];
    *(short8*)&gsL[o * 40 + i] = *(const short8*)&gl[ga];
  }
  // stage e2
  {
    int xr = tid >> 2, i = (tid & 3) * 8;
    int ea = (xq * 64 + xr) * 32 + i;
    *(short8*)&esH[xr * 40 + i] = *(const short8*)&e2h[ea];
    *(short8*)&esL[xr * 40 + i] = *(const short8*)&e2l[ea];
  }
  if (tid < 64) wbs[tid] = wb[tid];
  __syncthreads();

  short8 bh0 = *(const short8*)&hh[nb * 64 + lg * 8];
  short8 bh1 = *(const short8*)&hh[nb * 64 + 32 + lg * 8];
  int xr = wave * 16 + lm;
  short8 eh = *(const short8*)&esH[xr * 40 + lg * 8];
  short8 el = *(const short8*)&esL[xr * 40 + lg * 8];

  f32x4 acc[4];
#pragma unroll
  for (int mi = 0; mi < 4; ++mi) acc[mi] = (f32x4){0.f, 0.f, 0.f, 0.f};

#pragma unroll
  for (int mi = 0; mi < 4; ++mi) {
    int o = mi * 16 + lm;
    short8 ah0 = *(const short8*)&wsH[o * 72 + lg * 8];
    short8 al0 = *(const short8*)&wsL[o * 72 + lg * 8];
    acc[mi] = __builtin_amdgcn_mfma_f32_16x16x32_bf16(ah0, bh0, acc[mi], 0, 0, 0);
    acc[mi] = __builtin_amdgcn_mfma_f32_16x16x32_bf16(al0, bh0, acc[mi], 0, 0, 0);
    short8 ah1 = *(const short8*)&wsH[o * 72 + 32 + lg * 8];
    short8 al1 = *(const short8*)&wsL[o * 72 + 32 + lg * 8];
    acc[mi] = __builtin_amdgcn_mfma_f32_16x16x32_bf16(ah1, bh1, acc[mi], 0, 0, 0);
    acc[mi] = __builtin_amdgcn_mfma_f32_16x16x32_bf16(al1, bh1, acc[mi], 0, 0, 0);
    short8 gah = *(const short8*)&gsH[o * 40 + lg * 8];
    short8 gal = *(const short8*)&gsL[o * 40 + lg * 8];
    acc[mi] = __builtin_amdgcn_mfma_f32_16x16x32_bf16(gah, eh, acc[mi], 0, 0, 0);
    acc[mi] = __builtin_amdgcn_mfma_f32_16x16x32_bf16(gah, el, acc[mi], 0, 0, 0);
    acc[mi] = __builtin_amdgcn_mfma_f32_16x16x32_bf16(gal, eh, acc[mi], 0, 0, 0);
  }

  // epilogue: bias + GELU -> bf16 -> LDS [x][o] stride 66 (reuse wsH) -> coalesced stores
  __syncthreads();
  int xl = wave * 16 + lm;
#pragma unroll
  for (int mi = 0; mi < 4; ++mi) {
    ushort4 H;
#pragma unroll
    for (int r = 0; r < 4; ++r) {
      int o = mi * 16 + lg * 4 + r;
      float ge = gelu(acc[mi][r] + wbs[o]);
      ((ushort*)&H)[r] = (ushort)bf16rne(ge);
    }
    *(ushort4*)&wsH[xl * 66 + mi * 16 + lg * 4] = H;
  }
  __syncthreads();
  size_t rowbase = (size_t)(b * 256 + y) * 256 + xq * 64;
#pragma unroll
  for (int rep = 0; rep < 2; ++rep) {
    int ch = rep * 256 + tid;         // (pixel p, 16B chunk)
    int p = ch >> 3, off = (ch & 7) * 8;
    short8 vH = *(const short8*)&wsH[p * 66 + off];
    *(short8*)&oh[(rowbase + p) * 64 + off] = vH;
  }

  // fused partial x-DFT of h_next over this quarter: wave = c 16-slice
  if (do_dft) {
    f32x4 dacc[2];
    dacc[0] = (f32x4){0.f, 0.f, 0.f, 0.f};
    dacc[1] = (f32x4){0.f, 0.f, 0.f, 0.f};
#pragma unroll
    for (int kstep = 0; kstep < 2; ++kstep) {
      int xls = kstep * 32 + lg * 8;
      short8 bh;
#pragma unroll
      for (int i = 0; i < 8; ++i) {
        bh[i] = (short)wsH[(xls + i) * 66 + wave * 16 + lm];
      }
      int x0g = xq * 64 + xls;
#pragma unroll
      for (int mtile = 0; mtile < 2; ++mtile) {
        short8 ah = *(const short8*)&eah[(mtile * 16 + lm) * 256 + x0g];
        short8 al = *(const short8*)&eal[(mtile * 16 + lm) * 256 + x0g];
        dacc[mtile] = __builtin_amdgcn_mfma_f32_16x16x32_bf16(ah, bh, dacc[mtile], 0, 0, 0);
        dacc[mtile] = __builtin_amdgcn_mfma_f32_16x16x32_bf16(al, bh, dacc[mtile], 0, 0, 0);
      }
    }
    int c = wave * 16 + lm;
    size_t row = ((size_t)(b * 64 + c) * 256 + y) * 128 + xq * 32 + lg * 8;
    *(float4*)&A2[row] = make_float4(dacc[0][0], dacc[0][1], dacc[0][2], dacc[0][3]);
    *(float4*)&A2[row + 4] = make_float4(dacc[1][0], dacc[1][1], dacc[1][2], dacc[1][3]);
  }
}

// ---------- K_FINAL: LDS-staged fc1 weights. grid 4096 ----------
__global__ __launch_bounds__(256) void k_final(const ushort* __restrict__ hh,
                                               const ushort* __restrict__ w1h, const ushort* __restrict__ w1l,
                                               const float* __restrict__ b1, const float* __restrict__ w2,
                                               const float* __restrict__ b2, float* __restrict__ out) {
  int bid = blockIdx.x;                 // 4096 = b*1024 + y*4 + xq
  int b = bid >> 10, y = (bid >> 2) & 255, xq = bid & 3;
  int tid = threadIdx.x;
  int lane = tid & 63, wave = tid >> 6;
  int lm = lane & 15, lg = lane >> 4;
  int x = xq * 64 + wave * 16 + lm;
  size_t nb = (size_t)(b * 256 + y) * 256 + x;

  __shared__ __align__(16) ushort w1sH[128 * 72], w1sL[128 * 72];
  __shared__ float b1s[128], w2s[128];

#pragma unroll
  for (int rep = 0; rep < 4; ++rep) {
    int flat = rep * 2048 + tid * 8;
    int j = flat >> 6, cc = flat & 63;
    *(short8*)&w1sH[j * 72 + cc] = *(const short8*)&w1h[flat];
    *(short8*)&w1sL[j * 72 + cc] = *(const short8*)&w1l[flat];
  }
  if (tid < 128) { b1s[tid] = b1[tid]; w2s[tid] = w2[tid]; }
  __syncthreads();

  short8 bh0 = *(const short8*)&hh[nb * 64 + lg * 8];
  short8 bh1 = *(const short8*)&hh[nb * 64 + 32 + lg * 8];

  f32x4 acc[8];
#pragma unroll
  for (int mi = 0; mi < 8; ++mi) acc[mi] = (f32x4){0.f, 0.f, 0.f, 0.f};

#pragma unroll
  for (int mi = 0; mi < 8; ++mi) {
    int j = mi * 16 + lm;
    short8 ah0 = *(const short8*)&w1sH[j * 72 + lg * 8];
    short8 al0 = *(const short8*)&w1sL[j * 72 + lg * 8];
    acc[mi] = __builtin_amdgcn_mfma_f32_16x16x32_bf16(ah0, bh0, acc[mi], 0, 0, 0);
    acc[mi] = __builtin_amdgcn_mfma_f32_16x16x32_bf16(al0, bh0, acc[mi], 0, 0, 0);
    short8 ah1 = *(const short8*)&w1sH[j * 72 + 32 + lg * 8];
    short8 al1 = *(const short8*)&w1sL[j * 72 + 32 + lg * 8];
    acc[mi] = __builtin_amdgcn_mfma_f32_16x16x32_bf16(ah1, bh1, acc[mi], 0, 0, 0);
    acc[mi] = __builtin_amdgcn_mfma_f32_16x16x32_bf16(al1, bh1, acc[mi], 0, 0, 0);
  }

  float p = 0.f;
#pragma unroll
  for (int mi = 0; mi < 8; ++mi)
#pragma unroll
    for (int r = 0; r < 4; ++r) {
      int j = mi * 16 + lg * 4 + r;
      p += w2s[j] * gelu(acc[mi][r] + b1s[j]);
    }
  p += __shfl_xor(p, 16);
  p += __shfl_xor(p, 32);
  if (lg == 0) {
    out[(b * 256 + y) * 256 + x] = p + b2[0];
  }
}

extern "C" void kernel_launch(void* const* d_in, const int* in_sizes, int n_in,
                              void* d_out, int out_size, void* d_ws, size_t ws_size,
                              hipStream_t stream) {
  const float* x       = (const float*)d_in[0];
  const float* fc0_w   = (const float*)d_in[1];
  const float* fc0_b   = (const float*)d_in[2];
  const float* spec_wr = (const float*)d_in[3];
  const float* spec_wi = (const float*)d_in[4];
  const float* w_w     = (const float*)d_in[5];
  const float* w_b     = (const float*)d_in[6];
  const float* fc1_w   = (const float*)d_in[7];
  const float* fc1_b   = (const float*)d_in[8];
  const float* fc2_w   = (const float*)d_in[9];
  const float* fc2_b   = (const float*)d_in[10];
  float* out = (float*)d_out;

  char* ws = (char*)d_ws;
  ushort* h0h  = (ushort*)ws;                              // 33554432 B
  ushort* h1h  = (ushort*)(ws + 33554432);                 // 33554432 B
  float*  A2   = (float*)(ws + 67108864);                  // 33554432 B
  ushort* gh   = (ushort*)(ws + 100663296);                // 4194304 B
  ushort* gl   = (ushort*)(ws + 104857600);                // 4194304 B
  float2* X    = (float2*)(ws + 109051904);                // 524288 B
  float2* Y    = (float2*)(ws + 109576192);                // 524288 B
  float*  cosT = (float*)(ws + 110100480);                 // 16384 B
  float*  sinT = (float*)(ws + 110116864);                 // 16384 B
  ushort* eah  = (ushort*)(ws + 110133248);                // 16384 B
  ushort* eal  = (ushort*)(ws + 110149632);                // 16384 B
  ushort* e2h  = (ushort*)(ws + 110166016);                // 16384 B
  ushort* e2l  = (ushort*)(ws + 110182400);                // 16384 B
  ushort* wWh  = (ushort*)(ws + 110198784);                // 32768 B
  ushort* wWl  = (ushort*)(ws + 110231552);                // 32768 B
  ushort* w1h  = (ushort*)(ws + 110264320);                // 16384 B
  ushort* w1l  = (ushort*)(ws + 110280704);                // 16384 B

  k_tables<<<144, 256, 0, stream>>>(cosT, sinT, eah, eal, e2h, e2l,
                                    w_w, fc1_w, wWh, wWl, w1h, w1l);
  k_fc0<<<1024, 256, 0, stream>>>(x, fc0_w, fc0_b, eah, eal, h0h, A2);
  ushort* hch = h0h;
  ushort* hnh = h1h;
  for (int l = 0; l < 4; ++l) {
    k_f2<<<256, 256, 0, stream>>>(A2, cosT, sinT, X);
    k_mix<<<256, 256, 0, stream>>>(X, spec_wr + (size_t)l * 1048576, spec_wi + (size_t)l * 1048576, Y);
    k_inv1<<<256, 256, 0, stream>>>(Y, cosT, sinT, gh, gl);
    k_layer<<<4096, 256, 0, stream>>>(hch, gh, gl, wWh + l * 4096, wWl + l * 4096,
                                      w_b + l * 64, e2h, e2l, eah, eal, hnh, A2, (l < 3) ? 1 : 0);
    ushort* t = hch; hch = hnh; hnh = t;
  }
  k_final<<<4096, 256, 0, stream>>>(hch, w1h, w1l, fc1_b, fc2_w, fc2_b, out);
}